// Round 2
// baseline (1767.359 us; speedup 1.0000x reference)
//
#include <hip/hip_runtime.h>
#include <hip/hip_bf16.h>

// TreeLSTM, 128 perfect binary trees, depth 9, H=256. N=130944 nodes.
//
// Structure:
//   - iou0=(x@W_iou)*mask is only consumed at LEAVES (internal nodes overwrite
//     iou with h_cat@U_iou) -> W_iou GEMM done for 65536 leaf rows only.
//   - States h/c/mh are only consumed by the immediate parent level and logits
//     are emitted at apply time -> store states COMPACTED per level in two
//     ping-pong buffers (A: leaf-level size, B: half), never full-N.
//   - Trees are independent -> slab T trees at a time, T chosen at launch from
//     ws_size (128/64/32/16/8 -> 176/101/63/32/16 MB workspace).
//   - GEMM intermediate `lin` chunked to <=16384(leaf)/8192(level) rows.
//
// ws layout (bf16): hA,cA,mhA [T*512*256 each] hB,cB,mhB [T*256*256 each]
//                   lin [max(min(T*512,16384)*768, min(T*256,8192)*1280)]

#define NTREES 128
#define NPT    1023
#define HS     256

typedef __hip_bfloat16 bf16;
typedef unsigned short us8 __attribute__((ext_vector_type(8)));

__device__ __forceinline__ float bits2f(unsigned short b) {
    return __uint_as_float(((unsigned)b) << 16);
}
__device__ __forceinline__ float ld_bf(const bf16* p) {
    return bits2f(*reinterpret_cast<const unsigned short*>(p));
}
__device__ __forceinline__ unsigned short f2bits(float x) {
    bf16 h = __float2bfloat16(x);
    return *reinterpret_cast<unsigned short*>(&h);
}
__device__ __forceinline__ float sigm(float x) { return 1.0f / (1.0f + expf(-x)); }

// ---------------------------------------------------------------------------
// Leaf GEMM: lin[rc, 0:768] = emb[wordid[node]] @ W_iou  (zero if mask=0)
// 64x64 tile, BK=32, 256 threads, 4x4 microtile. rc = chunk-local row.
// ---------------------------------------------------------------------------
__global__ __launch_bounds__(256) void leaf_gemm(
    const int* __restrict__ wordid, const int* __restrict__ mask,
    const float* __restrict__ emb, const float* __restrict__ W,
    bf16* __restrict__ lin, const int g0)
{
    __shared__ __align__(16) float a_s[32][68];
    __shared__ __align__(16) float b_s[32][68];
    const int t    = threadIdx.x;
    const int bm0  = blockIdx.x * 64;
    const int bn0  = blockIdx.y * 64;
    const int trow = t >> 4, tcol = t & 15;

    const int arow = t >> 2;           // A-stage: 64 rows x 32 k, 8 floats/thread
    const int ak0  = (t & 3) * 8;
    const int gr   = g0 + bm0 + arow;  // global leaf row
    const int tree = gr >> 9, idx = gr & 511;
    const int node = tree * NPT + 511 + idx;
    const int m    = mask[node];
    const float* aptr = emb + (long)wordid[node] * HS;

    const int bk    = t >> 3;          // B-stage: 32 k x 64 cols
    const int bcol0 = (t & 7) * 8;

    float acc[4][4] = {};

    for (int kt = 0; kt < 256; kt += 32) {
        __syncthreads();
        if (m) {
            const float4 v0 = *(const float4*)(aptr + kt + ak0);
            const float4 v1 = *(const float4*)(aptr + kt + ak0 + 4);
            a_s[ak0+0][arow] = v0.x; a_s[ak0+1][arow] = v0.y;
            a_s[ak0+2][arow] = v0.z; a_s[ak0+3][arow] = v0.w;
            a_s[ak0+4][arow] = v1.x; a_s[ak0+5][arow] = v1.y;
            a_s[ak0+6][arow] = v1.z; a_s[ak0+7][arow] = v1.w;
        } else {
            #pragma unroll
            for (int i = 0; i < 8; ++i) a_s[ak0+i][arow] = 0.0f;
        }
        {
            const float* bp = W + (long)(kt + bk) * 768 + bn0 + bcol0;
            const float4 w0 = *(const float4*)bp;
            const float4 w1 = *(const float4*)(bp + 4);
            b_s[bk][bcol0+0] = w0.x; b_s[bk][bcol0+1] = w0.y;
            b_s[bk][bcol0+2] = w0.z; b_s[bk][bcol0+3] = w0.w;
            b_s[bk][bcol0+4] = w1.x; b_s[bk][bcol0+5] = w1.y;
            b_s[bk][bcol0+6] = w1.z; b_s[bk][bcol0+7] = w1.w;
        }
        __syncthreads();
        #pragma unroll
        for (int kk = 0; kk < 32; ++kk) {
            const float4 av = *(const float4*)&a_s[kk][trow * 4];
            const float4 bv = *(const float4*)&b_s[kk][tcol * 4];
            acc[0][0] += av.x * bv.x; acc[0][1] += av.x * bv.y;
            acc[0][2] += av.x * bv.z; acc[0][3] += av.x * bv.w;
            acc[1][0] += av.y * bv.x; acc[1][1] += av.y * bv.y;
            acc[1][2] += av.y * bv.z; acc[1][3] += av.y * bv.w;
            acc[2][0] += av.z * bv.x; acc[2][1] += av.z * bv.y;
            acc[2][2] += av.z * bv.z; acc[2][3] += av.z * bv.w;
            acc[3][0] += av.w * bv.x; acc[3][1] += av.w * bv.y;
            acc[3][2] += av.w * bv.z; acc[3][3] += av.w * bv.w;
        }
    }
    #pragma unroll
    for (int i = 0; i < 4; ++i) {
        const int rr = bm0 + trow * 4 + i;      // chunk-local
        bf16* op = lin + (long)rr * 768 + bn0 + tcol * 4;
        ushort4 pk;
        pk.x = f2bits(acc[i][0]); pk.y = f2bits(acc[i][1]);
        pk.z = f2bits(acc[i][2]); pk.w = f2bits(acc[i][3]);
        *reinterpret_cast<ushort4*>(op) = pk;
    }
}

// ---------------------------------------------------------------------------
// Level GEMM: lin[rc, 0:1280] = h_cat[p] @ [U_f_w(512x512) | U_iou(512x768)]
// h_cat[p][k] = k<256 ? h_child[cls][k] : h_child[cls+1][k-256]
// p = p0 + chunk-local row (slab-local parent row). Rows >= M clamped.
// ---------------------------------------------------------------------------
__global__ __launch_bounds__(256) void level_gemm(
    const bf16* __restrict__ h_child,
    const float* __restrict__ U_f_w, const float* __restrict__ U_iou,
    bf16* __restrict__ lin, const int lvl, const int p0, const int M)
{
    __shared__ __align__(16) float a_s[32][68];
    __shared__ __align__(16) float b_s[32][68];
    const int t    = threadIdx.x;
    const int bm0  = blockIdx.x * 64;
    const int bn0g = blockIdx.y * 64;      // 0..1279

    const float* B; int ldb, bc0;
    if (bn0g < 512) { B = U_f_w; ldb = 512; bc0 = bn0g; }
    else            { B = U_iou; ldb = 768; bc0 = bn0g - 512; }

    const int trow = t >> 4, tcol = t & 15;
    const int arow = t >> 2, ak0 = (t & 3) * 8;
    int p = p0 + bm0 + arow;
    if (p >= M) p = M - 1;                 // clamp: safe reads, stores guarded
    const int tl   = p >> lvl;
    const int idx  = p & ((1 << lvl) - 1);
    const int cls  = tl * (2 << lvl) + 2 * idx;   // slab-local left-child row

    const int bk    = t >> 3;
    const int bcol0 = (t & 7) * 8;

    float acc[4][4] = {};

    for (int kt = 0; kt < 512; kt += 32) {
        __syncthreads();
        {
            const int kg = kt + ak0;             // multiple of 8, single child
            const int cr = cls + (kg >> 8);
            const int ko = kg & 255;
            const us8 u = *(const us8*)(h_child + (long)cr * HS + ko);
            #pragma unroll
            for (int i = 0; i < 8; ++i) a_s[ak0+i][arow] = bits2f(u[i]);
        }
        {
            const float* bp = B + (long)(kt + bk) * ldb + bc0 + bcol0;
            const float4 w0 = *(const float4*)bp;
            const float4 w1 = *(const float4*)(bp + 4);
            b_s[bk][bcol0+0] = w0.x; b_s[bk][bcol0+1] = w0.y;
            b_s[bk][bcol0+2] = w0.z; b_s[bk][bcol0+3] = w0.w;
            b_s[bk][bcol0+4] = w1.x; b_s[bk][bcol0+5] = w1.y;
            b_s[bk][bcol0+6] = w1.z; b_s[bk][bcol0+7] = w1.w;
        }
        __syncthreads();
        #pragma unroll
        for (int kk = 0; kk < 32; ++kk) {
            const float4 av = *(const float4*)&a_s[kk][trow * 4];
            const float4 bv = *(const float4*)&b_s[kk][tcol * 4];
            acc[0][0] += av.x * bv.x; acc[0][1] += av.x * bv.y;
            acc[0][2] += av.x * bv.z; acc[0][3] += av.x * bv.w;
            acc[1][0] += av.y * bv.x; acc[1][1] += av.y * bv.y;
            acc[1][2] += av.y * bv.z; acc[1][3] += av.y * bv.w;
            acc[2][0] += av.z * bv.x; acc[2][1] += av.z * bv.y;
            acc[2][2] += av.z * bv.z; acc[2][3] += av.z * bv.w;
            acc[3][0] += av.w * bv.x; acc[3][1] += av.w * bv.y;
            acc[3][2] += av.w * bv.z; acc[3][3] += av.w * bv.w;
        }
    }
    #pragma unroll
    for (int i = 0; i < 4; ++i) {
        const int rrc = bm0 + trow * 4 + i;     // chunk-local
        if (p0 + rrc < M) {
            bf16* op = lin + (long)rrc * 1280 + bn0g + tcol * 4;
            ushort4 pk;
            pk.x = f2bits(acc[i][0]); pk.y = f2bits(acc[i][1]);
            pk.z = f2bits(acc[i][2]); pk.w = f2bits(acc[i][3]);
            *reinterpret_cast<ushort4*>(op) = pk;
        }
    }
}

// ---------------------------------------------------------------------------
// Fused per-node logits: out[node,0:4] = (h+mh) @ lin_w + lin_b
// ---------------------------------------------------------------------------
__device__ __forceinline__ void logits_reduce(
    float s, const float* __restrict__ lin_w, const float* __restrict__ lin_b,
    float* __restrict__ outp, int j)
{
    const float4 w = *(const float4*)(lin_w + j * 4);
    float p0 = s * w.x, p1 = s * w.y, p2 = s * w.z, p3 = s * w.w;
    #pragma unroll
    for (int off = 32; off > 0; off >>= 1) {
        p0 += __shfl_down(p0, off);
        p1 += __shfl_down(p1, off);
        p2 += __shfl_down(p2, off);
        p3 += __shfl_down(p3, off);
    }
    __shared__ float red[4][4];
    const int w_id = j >> 6, lane = j & 63;
    if (lane == 0) { red[w_id][0] = p0; red[w_id][1] = p1; red[w_id][2] = p2; red[w_id][3] = p3; }
    __syncthreads();
    if (j < 4) {
        outp[j] = red[0][j] + red[1][j] + red[2][j] + red[3][j] + lin_b[j];
    }
}

__global__ __launch_bounds__(256) void leaf_epi(
    const int* __restrict__ mask, const bf16* __restrict__ lin,
    const float* __restrict__ b_iou,
    const float* __restrict__ lin_w, const float* __restrict__ lin_b,
    bf16* __restrict__ h_s, bf16* __restrict__ c_s, bf16* __restrict__ mh_s,
    float* __restrict__ out, const int g0, const int s0)
{
    const int rc   = blockIdx.x;           // chunk-local row
    const int gr   = g0 + rc;              // global leaf row
    const int tree = gr >> 9, idx = gr & 511;
    const int node = tree * NPT + 511 + idx;
    const int j    = threadIdx.x;
    const int m    = mask[node];
    const bf16* lr = lin + (long)rc * 768;

    const float pi = (m ? ld_bf(lr + j)       : 0.0f) + b_iou[j];
    const float po = (m ? ld_bf(lr + 256 + j) : 0.0f) + b_iou[256 + j];
    const float pu = (m ? ld_bf(lr + 512 + j) : 0.0f) + b_iou[512 + j];
    const float iv = sigm(pi), ov = sigm(po), uv = tanhf(pu);
    const float cv  = iv * uv;
    const float hv  = ov * tanhf(cv);
    const float mhv = fmaxf(hv, 0.0f);

    const long o = (long)(s0 + rc) * HS + j;   // slab-local state row
    h_s[o]  = __float2bfloat16(hv);
    c_s[o]  = __float2bfloat16(cv);
    mh_s[o] = __float2bfloat16(mhv);

    logits_reduce(hv + mhv, lin_w, lin_b, out + (long)node * 4, j);
}

__global__ __launch_bounds__(256) void level_epi(
    const bf16* __restrict__ lin,
    const float* __restrict__ b_iou, const float* __restrict__ U_f_b,
    const float* __restrict__ lin_w, const float* __restrict__ lin_b,
    const bf16* __restrict__ c_c, const bf16* __restrict__ mh_c,
    bf16* __restrict__ h_p, bf16* __restrict__ c_p, bf16* __restrict__ mh_p,
    float* __restrict__ out, const int lvl, const int p0, const int tree0)
{
    const int rc   = blockIdx.x;               // chunk-local
    const int p    = p0 + rc;                  // slab-local parent row
    const int tl   = p >> lvl, idx = p & ((1 << lvl) - 1);
    const int node = (tree0 + tl) * NPT + (1 << lvl) - 1 + idx;
    const int cls  = tl * (2 << lvl) + 2 * idx;
    const int j    = threadIdx.x;
    const bf16* lr = lin + (long)rc * 1280;

    const float fl = sigm(ld_bf(lr + j)       + U_f_b[j]);
    const float fr = sigm(ld_bf(lr + 256 + j) + U_f_b[256 + j]);
    const float pi = ld_bf(lr + 512 + j)  + b_iou[j];
    const float po = ld_bf(lr + 768 + j)  + b_iou[256 + j];
    const float pu = ld_bf(lr + 1024 + j) + b_iou[512 + j];

    const float ccl = ld_bf(c_c  + (long)cls * HS + j);
    const float ccr = ld_bf(c_c  + (long)(cls + 1) * HS + j);
    const float mhl = ld_bf(mh_c + (long)cls * HS + j);
    const float mhr = ld_bf(mh_c + (long)(cls + 1) * HS + j);

    const float c_red  = fl * ccl + fr * ccr;
    const float mh_red = fmaxf(mhl, mhr);

    const float iv = sigm(pi), ov = sigm(po), uv = tanhf(pu);
    const float cv  = iv * uv + c_red;
    const float hv  = ov * tanhf(cv);
    const float mhv = fmaxf(hv, mh_red);

    const long o = (long)p * HS + j;           // slab-local parent state row
    h_p[o]  = __float2bfloat16(hv);
    c_p[o]  = __float2bfloat16(cv);
    mh_p[o] = __float2bfloat16(mhv);

    logits_reduce(hv + mhv, lin_w, lin_b, out + (long)node * 4, j);
}

// ---------------------------------------------------------------------------
extern "C" void kernel_launch(void* const* d_in, const int* in_sizes, int n_in,
                              void* d_out, int out_size, void* d_ws, size_t ws_size,
                              hipStream_t stream) {
    const int*   wordid = (const int*)d_in[0];
    const int*   mask   = (const int*)d_in[1];
    const float* emb    = (const float*)d_in[2];
    const float* W_iou  = (const float*)d_in[3];
    const float* U_iou  = (const float*)d_in[4];
    const float* U_f_w  = (const float*)d_in[5];
    const float* U_f_b  = (const float*)d_in[6];
    const float* b_iou  = (const float*)d_in[7];
    const float* lin_w  = (const float*)d_in[8];
    const float* lin_b  = (const float*)d_in[9];
    float* out = (float*)d_out;

    // Pick largest tree-slab T that fits ws_size (deterministic across calls).
    auto lin_elems = [](int T) -> size_t {
        size_t le = (size_t)(T * 512 < 16384 ? T * 512 : 16384) * 768;
        size_t lv = (size_t)(T * 256 < 8192  ? T * 256 : 8192)  * 1280;
        return le > lv ? le : lv;
    };
    auto need = [&](int T) -> size_t {
        return ((size_t)T * 512 * HS * 3 + (size_t)T * 256 * HS * 3 + lin_elems(T)) * 2;
    };
    int T = 8;
    const int cands[4] = {128, 64, 32, 16};
    for (int ci = 0; ci < 4; ++ci) {
        if (need(cands[ci]) <= ws_size) { T = cands[ci]; break; }
    }

    const size_t aR = (size_t)T * 512 * HS;   // elems per A-set array
    const size_t bR = (size_t)T * 256 * HS;
    bf16* hA  = (bf16*)d_ws;
    bf16* cA  = hA  + aR;
    bf16* mhA = cA  + aR;
    bf16* hB  = mhA + aR;
    bf16* cB  = hB  + bR;
    bf16* mhB = cB  + bR;
    bf16* lin = mhB + bR;

    for (int tree0 = 0; tree0 < NTREES; tree0 += T) {
        // ---- leaves -> A
        const int Ml  = T * 512;
        const int CRl = Ml < 16384 ? Ml : 16384;
        for (int r0 = 0; r0 < Ml; r0 += CRl) {
            const int g0 = tree0 * 512 + r0;
            leaf_gemm<<<dim3(CRl / 64, 12), 256, 0, stream>>>(
                wordid, mask, emb, W_iou, lin, g0);
            leaf_epi<<<CRl, 256, 0, stream>>>(
                mask, lin, b_iou, lin_w, lin_b, hA, cA, mhA, out, g0, r0);
        }
        // ---- internal levels, bottom-up; ping-pong A<->B
        bool childIsA = true;
        for (int l = 8; l >= 0; --l) {
            bf16 *hc, *cc, *mc, *hp, *cp, *mp;
            if (childIsA) { hc = hA; cc = cA; mc = mhA; hp = hB; cp = cB; mp = mhB; }
            else          { hc = hB; cc = cB; mc = mhB; hp = hA; cp = cA; mp = mhA; }
            const int M   = T << l;
            const int CRv = M < 8192 ? M : 8192;
            for (int p0 = 0; p0 < M; p0 += CRv) {
                level_gemm<<<dim3((CRv + 63) / 64, 20), 256, 0, stream>>>(
                    hc, U_f_w, U_iou, lin, l, p0, M);
                level_epi<<<CRv, 256, 0, stream>>>(
                    lin, b_iou, U_f_b, lin_w, lin_b, cc, mc, hp, cp, mp,
                    out, l, p0, tree0);
            }
            childIsA = !childIsA;
        }
    }
}

// Round 3
// 623.541 us; speedup vs baseline: 2.8344x; 2.8344x over previous
//
#include <hip/hip_runtime.h>
#include <hip/hip_bf16.h>

// TreeLSTM, 128 perfect binary trees, depth 9, H=256. N=130944 nodes.
//
//   - iou0=(x@W_iou)*mask only consumed at LEAVES -> leaf-only W_iou GEMM.
//   - States compacted per level, ping-pong A/B buffers; trees slabbed by T
//     chosen from ws_size.
//   - GEMMs use bf16 MFMA (v_mfma_f32_16x16x32_bf16), fp32 accumulate.
//     Weights pre-converted+transposed to bf16 once per launch:
//       Wt[768][256]  = W_iou^T
//       Ut[1280][512] = [U_f_w | U_iou]^T
//     Both GEMMs: C[M][N] = A[M][K] @ Bt[N][K]^T, 128x128 tile, BK=32,
//     4 waves (2x2), 4x4 MFMA fragments per wave.
//
// ws layout (bf16): Wt, Ut, hA,cA,mhA [T*512*256], hB,cB,mhB [T*256*256],
//                   lin [max(min(T*512,16384)*768, min(T*256,8192)*1280)]

#define NTREES 128
#define NPT    1023
#define HS     256

typedef __hip_bfloat16 bf16;
typedef unsigned short us8 __attribute__((ext_vector_type(8)));
typedef short bf16x8 __attribute__((ext_vector_type(8)));
typedef float f32x4 __attribute__((ext_vector_type(4)));

__device__ __forceinline__ float bits2f(unsigned short b) {
    return __uint_as_float(((unsigned)b) << 16);
}
__device__ __forceinline__ float ld_bf(const bf16* p) {
    return bits2f(*reinterpret_cast<const unsigned short*>(p));
}
__device__ __forceinline__ unsigned short f2bits(float x) {
    bf16 h = __float2bfloat16(x);
    return *reinterpret_cast<unsigned short*>(&h);
}
__device__ __forceinline__ float sigm(float x) { return 1.0f / (1.0f + expf(-x)); }

// ---------------------------------------------------------------------------
// Weight prep: Wt[n][k] = W_iou[k][n] (768x256), Ut[n][k] = cat(U_f_w,U_iou)^T
// ---------------------------------------------------------------------------
#define WT_ELEMS (768 * 256)
#define UT_ELEMS (1280 * 512)

__global__ __launch_bounds__(256) void prep_w(
    const float* __restrict__ W_iou, const float* __restrict__ U_f_w,
    const float* __restrict__ U_iou, bf16* __restrict__ Wt, bf16* __restrict__ Ut)
{
    const int i = blockIdx.x * 256 + threadIdx.x;
    if (i < WT_ELEMS) {
        const int n = i >> 8, k = i & 255;
        Wt[i] = __float2bfloat16(W_iou[k * 768 + n]);
    } else if (i < WT_ELEMS + UT_ELEMS) {
        const int j = i - WT_ELEMS;
        const int n = j >> 9, k = j & 511;
        const float v = (n < 512) ? U_f_w[k * 512 + n] : U_iou[k * 768 + (n - 512)];
        Ut[j] = __float2bfloat16(v);
    }
}

// ---------------------------------------------------------------------------
// Leaf MFMA GEMM: lin[rc,0:768] = bf16(emb[wordid[node]]) @ Wt^T  (0 if !mask)
// ---------------------------------------------------------------------------
__global__ __launch_bounds__(256) void leaf_gemm_mfma(
    const int* __restrict__ wordid, const int* __restrict__ mask,
    const float* __restrict__ emb, const bf16* __restrict__ Wt,
    bf16* __restrict__ lin, const int g0)
{
    __shared__ __align__(16) short a_s[128 * 40];
    __shared__ __align__(16) short b_s[128 * 40];
    const int t   = threadIdx.x;
    const int bm0 = blockIdx.x * 128;
    const int bn0 = blockIdx.y * 128;

    // staging: thread -> (row 0..127, k-half 0/16)
    const int srow = t >> 1;
    const int sk   = (t & 1) << 4;
    const int gr   = g0 + bm0 + srow;
    const int tree = gr >> 9, idx = gr & 511;
    const int node = tree * NPT + 511 + idx;
    const int m_   = mask[node];
    const float* aptr = emb + (long)wordid[node] * HS;
    const bf16*  bptr = Wt + (long)(bn0 + srow) * 256;

    // fragments
    const int lane = t & 63, wave = t >> 6;
    const int wr = wave >> 1, wc = wave & 1;
    const int fr = lane & 15, l4 = lane >> 4;
    const short* a_rd = a_s + (wr * 64 + fr) * 40 + l4 * 8;
    const short* b_rd = b_s + (wc * 64 + fr) * 40 + l4 * 8;

    f32x4 acc[4][4];
    #pragma unroll
    for (int i = 0; i < 4; ++i)
        #pragma unroll
        for (int j = 0; j < 4; ++j) acc[i][j] = (f32x4){0.f, 0.f, 0.f, 0.f};

    for (int kt = 0; kt < 256; kt += 32) {
        __syncthreads();
        {
            short tmp[16];
            if (m_) {
                #pragma unroll
                for (int q = 0; q < 4; ++q) {
                    const float4 v = *(const float4*)(aptr + kt + sk + q * 4);
                    tmp[q*4+0] = (short)f2bits(v.x); tmp[q*4+1] = (short)f2bits(v.y);
                    tmp[q*4+2] = (short)f2bits(v.z); tmp[q*4+3] = (short)f2bits(v.w);
                }
            } else {
                #pragma unroll
                for (int q = 0; q < 16; ++q) tmp[q] = 0;
            }
            *(us8*)&a_s[srow * 40 + sk]     = *(us8*)&tmp[0];
            *(us8*)&a_s[srow * 40 + sk + 8] = *(us8*)&tmp[8];
            const us8 w0 = *(const us8*)(bptr + kt + sk);
            const us8 w1 = *(const us8*)(bptr + kt + sk + 8);
            *(us8*)&b_s[srow * 40 + sk]     = w0;
            *(us8*)&b_s[srow * 40 + sk + 8] = w1;
        }
        __syncthreads();
        bf16x8 af[4], bg[4];
        #pragma unroll
        for (int i = 0; i < 4; ++i) af[i] = *(const bf16x8*)(a_rd + i * 16 * 40);
        #pragma unroll
        for (int j = 0; j < 4; ++j) bg[j] = *(const bf16x8*)(b_rd + j * 16 * 40);
        #pragma unroll
        for (int i = 0; i < 4; ++i)
            #pragma unroll
            for (int j = 0; j < 4; ++j)
                acc[i][j] = __builtin_amdgcn_mfma_f32_16x16x32_bf16(
                    af[i], bg[j], acc[i][j], 0, 0, 0);
    }
    // C/D layout: col = lane&15, row = (lane>>4)*4 + q
    #pragma unroll
    for (int i = 0; i < 4; ++i) {
        const int row0 = bm0 + wr * 64 + i * 16 + l4 * 4;
        #pragma unroll
        for (int j = 0; j < 4; ++j) {
            const int col = bn0 + wc * 64 + j * 16 + fr;
            #pragma unroll
            for (int q = 0; q < 4; ++q)
                lin[(long)(row0 + q) * 768 + col] = __float2bfloat16(acc[i][j][q]);
        }
    }
}

// ---------------------------------------------------------------------------
// Level MFMA GEMM: lin[rc,0:1280] = h_cat[p] @ Ut^T
// h_cat contiguous: children are adjacent compacted rows (cls, cls+1).
// ---------------------------------------------------------------------------
__global__ __launch_bounds__(256) void level_gemm_mfma(
    const bf16* __restrict__ h_child, const bf16* __restrict__ Ut,
    bf16* __restrict__ lin, const int lvl, const int p0, const int M)
{
    __shared__ __align__(16) short a_s[128 * 40];
    __shared__ __align__(16) short b_s[128 * 40];
    const int t   = threadIdx.x;
    const int bm0 = blockIdx.x * 128;
    const int bn0 = blockIdx.y * 128;

    const int srow = t >> 1;
    const int sk   = (t & 1) << 4;
    int p = p0 + bm0 + srow;
    if (p >= M) p = M - 1;                       // clamp reads; stores guarded
    const int tl  = p >> lvl;
    const int idx = p & ((1 << lvl) - 1);
    const int cls = tl * (2 << lvl) + 2 * idx;   // slab-local left-child row
    const bf16* ha   = h_child + (long)cls * HS; // h_cat row, 512 contiguous
    const bf16* bptr = Ut + (long)(bn0 + srow) * 512;

    const int lane = t & 63, wave = t >> 6;
    const int wr = wave >> 1, wc = wave & 1;
    const int fr = lane & 15, l4 = lane >> 4;
    const short* a_rd = a_s + (wr * 64 + fr) * 40 + l4 * 8;
    const short* b_rd = b_s + (wc * 64 + fr) * 40 + l4 * 8;

    f32x4 acc[4][4];
    #pragma unroll
    for (int i = 0; i < 4; ++i)
        #pragma unroll
        for (int j = 0; j < 4; ++j) acc[i][j] = (f32x4){0.f, 0.f, 0.f, 0.f};

    for (int kt = 0; kt < 512; kt += 32) {
        __syncthreads();
        {
            const us8 a0 = *(const us8*)(ha + kt + sk);
            const us8 a1 = *(const us8*)(ha + kt + sk + 8);
            *(us8*)&a_s[srow * 40 + sk]     = a0;
            *(us8*)&a_s[srow * 40 + sk + 8] = a1;
            const us8 w0 = *(const us8*)(bptr + kt + sk);
            const us8 w1 = *(const us8*)(bptr + kt + sk + 8);
            *(us8*)&b_s[srow * 40 + sk]     = w0;
            *(us8*)&b_s[srow * 40 + sk + 8] = w1;
        }
        __syncthreads();
        bf16x8 af[4], bg[4];
        #pragma unroll
        for (int i = 0; i < 4; ++i) af[i] = *(const bf16x8*)(a_rd + i * 16 * 40);
        #pragma unroll
        for (int j = 0; j < 4; ++j) bg[j] = *(const bf16x8*)(b_rd + j * 16 * 40);
        #pragma unroll
        for (int i = 0; i < 4; ++i)
            #pragma unroll
            for (int j = 0; j < 4; ++j)
                acc[i][j] = __builtin_amdgcn_mfma_f32_16x16x32_bf16(
                    af[i], bg[j], acc[i][j], 0, 0, 0);
    }
    #pragma unroll
    for (int i = 0; i < 4; ++i) {
        const int row0 = bm0 + wr * 64 + i * 16 + l4 * 4;
        #pragma unroll
        for (int j = 0; j < 4; ++j) {
            const int col = bn0 + wc * 64 + j * 16 + fr;
            #pragma unroll
            for (int q = 0; q < 4; ++q) {
                const int rr = row0 + q;
                if (p0 + rr < M)
                    lin[(long)rr * 1280 + col] = __float2bfloat16(acc[i][j][q]);
            }
        }
    }
}

// ---------------------------------------------------------------------------
// Fused per-node logits: out[node,0:4] = (h+mh) @ lin_w + lin_b
// ---------------------------------------------------------------------------
__device__ __forceinline__ void logits_reduce(
    float s, const float* __restrict__ lin_w, const float* __restrict__ lin_b,
    float* __restrict__ outp, int j)
{
    const float4 w = *(const float4*)(lin_w + j * 4);
    float p0 = s * w.x, p1 = s * w.y, p2 = s * w.z, p3 = s * w.w;
    #pragma unroll
    for (int off = 32; off > 0; off >>= 1) {
        p0 += __shfl_down(p0, off);
        p1 += __shfl_down(p1, off);
        p2 += __shfl_down(p2, off);
        p3 += __shfl_down(p3, off);
    }
    __shared__ float red[4][4];
    const int w_id = j >> 6, lane = j & 63;
    if (lane == 0) { red[w_id][0] = p0; red[w_id][1] = p1; red[w_id][2] = p2; red[w_id][3] = p3; }
    __syncthreads();
    if (j < 4) {
        outp[j] = red[0][j] + red[1][j] + red[2][j] + red[3][j] + lin_b[j];
    }
}

__global__ __launch_bounds__(256) void leaf_epi(
    const int* __restrict__ mask, const bf16* __restrict__ lin,
    const float* __restrict__ b_iou,
    const float* __restrict__ lin_w, const float* __restrict__ lin_b,
    bf16* __restrict__ h_s, bf16* __restrict__ c_s, bf16* __restrict__ mh_s,
    float* __restrict__ out, const int g0, const int s0)
{
    const int rc   = blockIdx.x;
    const int gr   = g0 + rc;
    const int tree = gr >> 9, idx = gr & 511;
    const int node = tree * NPT + 511 + idx;
    const int j    = threadIdx.x;
    const int m    = mask[node];
    const bf16* lr = lin + (long)rc * 768;

    const float pi = (m ? ld_bf(lr + j)       : 0.0f) + b_iou[j];
    const float po = (m ? ld_bf(lr + 256 + j) : 0.0f) + b_iou[256 + j];
    const float pu = (m ? ld_bf(lr + 512 + j) : 0.0f) + b_iou[512 + j];
    const float iv = sigm(pi), ov = sigm(po), uv = tanhf(pu);
    const float cv  = iv * uv;
    const float hv  = ov * tanhf(cv);
    const float mhv = fmaxf(hv, 0.0f);

    const long o = (long)(s0 + rc) * HS + j;
    h_s[o]  = __float2bfloat16(hv);
    c_s[o]  = __float2bfloat16(cv);
    mh_s[o] = __float2bfloat16(mhv);

    logits_reduce(hv + mhv, lin_w, lin_b, out + (long)node * 4, j);
}

__global__ __launch_bounds__(256) void level_epi(
    const bf16* __restrict__ lin,
    const float* __restrict__ b_iou, const float* __restrict__ U_f_b,
    const float* __restrict__ lin_w, const float* __restrict__ lin_b,
    const bf16* __restrict__ c_c, const bf16* __restrict__ mh_c,
    bf16* __restrict__ h_p, bf16* __restrict__ c_p, bf16* __restrict__ mh_p,
    float* __restrict__ out, const int lvl, const int p0, const int tree0)
{
    const int rc   = blockIdx.x;
    const int p    = p0 + rc;
    const int tl   = p >> lvl, idx = p & ((1 << lvl) - 1);
    const int node = (tree0 + tl) * NPT + (1 << lvl) - 1 + idx;
    const int cls  = tl * (2 << lvl) + 2 * idx;
    const int j    = threadIdx.x;
    const bf16* lr = lin + (long)rc * 1280;

    const float fl = sigm(ld_bf(lr + j)       + U_f_b[j]);
    const float fr = sigm(ld_bf(lr + 256 + j) + U_f_b[256 + j]);
    const float pi = ld_bf(lr + 512 + j)  + b_iou[j];
    const float po = ld_bf(lr + 768 + j)  + b_iou[256 + j];
    const float pu = ld_bf(lr + 1024 + j) + b_iou[512 + j];

    const float ccl = ld_bf(c_c  + (long)cls * HS + j);
    const float ccr = ld_bf(c_c  + (long)(cls + 1) * HS + j);
    const float mhl = ld_bf(mh_c + (long)cls * HS + j);
    const float mhr = ld_bf(mh_c + (long)(cls + 1) * HS + j);

    const float c_red  = fl * ccl + fr * ccr;
    const float mh_red = fmaxf(mhl, mhr);

    const float iv = sigm(pi), ov = sigm(po), uv = tanhf(pu);
    const float cv  = iv * uv + c_red;
    const float hv  = ov * tanhf(cv);
    const float mhv = fmaxf(hv, mh_red);

    const long o = (long)p * HS + j;
    h_p[o]  = __float2bfloat16(hv);
    c_p[o]  = __float2bfloat16(cv);
    mh_p[o] = __float2bfloat16(mhv);

    logits_reduce(hv + mhv, lin_w, lin_b, out + (long)node * 4, j);
}

// ---------------------------------------------------------------------------
extern "C" void kernel_launch(void* const* d_in, const int* in_sizes, int n_in,
                              void* d_out, int out_size, void* d_ws, size_t ws_size,
                              hipStream_t stream) {
    const int*   wordid = (const int*)d_in[0];
    const int*   mask   = (const int*)d_in[1];
    const float* emb    = (const float*)d_in[2];
    const float* W_iou  = (const float*)d_in[3];
    const float* U_iou  = (const float*)d_in[4];
    const float* U_f_w  = (const float*)d_in[5];
    const float* U_f_b  = (const float*)d_in[6];
    const float* b_iou  = (const float*)d_in[7];
    const float* lin_w  = (const float*)d_in[8];
    const float* lin_b  = (const float*)d_in[9];
    float* out = (float*)d_out;

    const size_t wElems = (size_t)WT_ELEMS + UT_ELEMS;   // 851,968
    auto lin_elems = [](int T) -> size_t {
        size_t le = (size_t)(T * 512 < 16384 ? T * 512 : 16384) * 768;
        size_t lv = (size_t)(T * 256 < 8192  ? T * 256 : 8192)  * 1280;
        return le > lv ? le : lv;
    };
    auto need = [&](int T) -> size_t {
        return (wElems + (size_t)T * 512 * HS * 3 + (size_t)T * 256 * HS * 3
                + lin_elems(T)) * 2;
    };
    int T = 8;
    const int cands[4] = {128, 64, 32, 16};
    for (int ci = 0; ci < 4; ++ci) {
        if (need(cands[ci]) <= ws_size) { T = cands[ci]; break; }
    }

    bf16* Wt = (bf16*)d_ws;
    bf16* Ut = Wt + WT_ELEMS;
    const size_t aR = (size_t)T * 512 * HS;
    const size_t bR = (size_t)T * 256 * HS;
    bf16* hA  = Ut  + UT_ELEMS;
    bf16* cA  = hA  + aR;
    bf16* mhA = cA  + aR;
    bf16* hB  = mhA + aR;
    bf16* cB  = hB  + bR;
    bf16* mhB = cB  + bR;
    bf16* lin = mhB + bR;

    prep_w<<<(int)((wElems + 255) / 256), 256, 0, stream>>>(
        W_iou, U_f_w, U_iou, Wt, Ut);

    for (int tree0 = 0; tree0 < NTREES; tree0 += T) {
        // ---- leaves -> A
        const int Ml  = T * 512;
        const int CRl = Ml < 16384 ? Ml : 16384;
        for (int r0 = 0; r0 < Ml; r0 += CRl) {
            const int g0 = tree0 * 512 + r0;
            leaf_gemm_mfma<<<dim3(CRl / 128, 6), 256, 0, stream>>>(
                wordid, mask, emb, Wt, lin, g0);
            leaf_epi<<<CRl, 256, 0, stream>>>(
                mask, lin, b_iou, lin_w, lin_b, hA, cA, mhA, out, g0, r0);
        }
        // ---- internal levels, bottom-up; ping-pong A<->B
        bool childIsA = true;
        for (int l = 8; l >= 0; --l) {
            bf16 *hc, *cc, *mc, *hp, *cp, *mp;
            if (childIsA) { hc = hA; cc = cA; mc = mhA; hp = hB; cp = cB; mp = mhB; }
            else          { hc = hB; cc = cB; mc = mhB; hp = hA; cp = cA; mp = mhA; }
            const int M   = T << l;
            const int CRv = M < 8192 ? M : 8192;
            for (int p0 = 0; p0 < M; p0 += CRv) {
                level_gemm_mfma<<<dim3((CRv + 127) / 128, 10), 256, 0, stream>>>(
                    hc, Ut, lin, l, p0, M);
                level_epi<<<CRv, 256, 0, stream>>>(
                    lin, b_iou, U_f_b, lin_w, lin_b, cc, mc, hp, cp, mp,
                    out, l, p0, tree0);
            }
            childIsA = !childIsA;
        }
    }
}

// Round 4
// 522.873 us; speedup vs baseline: 3.3801x; 1.1925x over previous
//
#include <hip/hip_runtime.h>
#include <hip/hip_bf16.h>

// TreeLSTM, 128 perfect binary trees, depth 9, H=256. N=130944 nodes.
//
//   - iou0=(x@W_iou)*mask only consumed at LEAVES -> leaf-only W_iou GEMM.
//   - States compacted per level, ping-pong A/B buffers; trees slabbed by T
//     chosen from ws_size (T=128 + unchunked lin fits in 256 MiB).
//   - GEMMs: bf16 MFMA (16x16x32), m97 structure: 128x128 tile, BK=32,
//     4 waves (2x2), LINEAR [128][32] LDS tiles, global_load_lds width=16
//     staging for B (weights) and level-A (h_cat = contiguous row since
//     compacted children are adjacent). Leaf-A register-staged (fp32->bf16
//     convert + mask zeroing) with lane-linear ds_write_b128.
//   - Weights pre-transposed to bf16: Wt[768][256], Ut[1280][512].

#define NTREES 128
#define NPT    1023
#define HS     256

typedef __hip_bfloat16 bf16;
typedef unsigned short us8 __attribute__((ext_vector_type(8)));
typedef short bf16x8 __attribute__((ext_vector_type(8)));
typedef float f32x4 __attribute__((ext_vector_type(4)));

typedef __attribute__((address_space(1))) const void gvoid;
typedef __attribute__((address_space(3))) void svoid;
#define GLD16(gp, lp) \
    __builtin_amdgcn_global_load_lds((gvoid*)(gp), (svoid*)(lp), 16, 0, 0)

__device__ __forceinline__ float bits2f(unsigned short b) {
    return __uint_as_float(((unsigned)b) << 16);
}
__device__ __forceinline__ float ld_bf(const bf16* p) {
    return bits2f(*reinterpret_cast<const unsigned short*>(p));
}
__device__ __forceinline__ unsigned short f2bits(float x) {
    bf16 h = __float2bfloat16(x);
    return *reinterpret_cast<unsigned short*>(&h);
}
__device__ __forceinline__ float sigm(float x) { return 1.0f / (1.0f + expf(-x)); }

// ---------------------------------------------------------------------------
// Weight prep: Wt[n][k] = W_iou[k][n] (768x256), Ut[n][k] = cat(U_f_w,U_iou)^T
// ---------------------------------------------------------------------------
#define WT_ELEMS (768 * 256)
#define UT_ELEMS (1280 * 512)

__global__ __launch_bounds__(256) void prep_w(
    const float* __restrict__ W_iou, const float* __restrict__ U_f_w,
    const float* __restrict__ U_iou, bf16* __restrict__ Wt, bf16* __restrict__ Ut)
{
    const int i = blockIdx.x * 256 + threadIdx.x;
    if (i < WT_ELEMS) {
        const int n = i >> 8, k = i & 255;
        Wt[i] = __float2bfloat16(W_iou[k * 768 + n]);
    } else if (i < WT_ELEMS + UT_ELEMS) {
        const int j = i - WT_ELEMS;
        const int n = j >> 9, k = j & 511;
        const float v = (n < 512) ? U_f_w[k * 512 + n] : U_iou[k * 768 + (n - 512)];
        Ut[j] = __float2bfloat16(v);
    }
}

// ---------------------------------------------------------------------------
// Leaf MFMA GEMM: lin[rc,0:768] = bf16(emb[wordid[node]]) @ Wt^T  (0 if !mask)
// ---------------------------------------------------------------------------
__global__ __launch_bounds__(256) void leaf_gemm_mfma(
    const int* __restrict__ wordid, const int* __restrict__ mask,
    const float* __restrict__ emb, const bf16* __restrict__ Wt,
    bf16* __restrict__ lin, const int g0)
{
    __shared__ __align__(16) short a_s[128 * 32];
    __shared__ __align__(16) short b_s[128 * 32];
    const int t    = threadIdx.x;
    const int bm0  = blockIdx.x * 128;
    const int bn0  = blockIdx.y * 128;
    const int lane = t & 63, wave = t >> 6;

    // A register-staging mapping: pass p in {0,1}: row = p*64 + t/4, k8=(t%4)*8
    const int arow_lo = t >> 2;          // 0..63
    const int k8t     = (t & 3) * 8;
    const float* aptr[2];
    int amask[2];
    #pragma unroll
    for (int p = 0; p < 2; ++p) {
        const int row  = p * 64 + arow_lo;
        const int gr   = g0 + bm0 + row;
        const int tree = gr >> 9, idx = gr & 511;
        const int node = tree * NPT + 511 + idx;
        amask[p] = mask[node];
        aptr[p]  = emb + (long)wordid[node] * HS + k8t;
    }

    // B global_load_lds: instruction n = wave*2+q covers LDS rows n*16+lane/4
    const int l4a = lane >> 2;
    const int k8  = (lane & 3) * 8;
    const bf16* bSrc[2];
    #pragma unroll
    for (int q = 0; q < 2; ++q) {
        const int n = wave * 2 + q;
        bSrc[q] = Wt + (long)(bn0 + n * 16 + l4a) * 256 + k8;
    }

    const int wr = wave >> 1, wc = wave & 1;
    const int fr = lane & 15, l4 = lane >> 4;

    f32x4 acc[4][4];
    #pragma unroll
    for (int i = 0; i < 4; ++i)
        #pragma unroll
        for (int j = 0; j < 4; ++j) acc[i][j] = (f32x4){0.f, 0.f, 0.f, 0.f};

    for (int kt = 0; kt < 256; kt += 32) {
        __syncthreads();
        #pragma unroll
        for (int q = 0; q < 2; ++q)
            GLD16(bSrc[q] + kt, &b_s[(wave * 2 + q) * 512]);
        #pragma unroll
        for (int p = 0; p < 2; ++p) {
            short tmp[8];
            if (amask[p]) {
                const float4 v0 = *(const float4*)(aptr[p] + kt);
                const float4 v1 = *(const float4*)(aptr[p] + kt + 4);
                tmp[0] = (short)f2bits(v0.x); tmp[1] = (short)f2bits(v0.y);
                tmp[2] = (short)f2bits(v0.z); tmp[3] = (short)f2bits(v0.w);
                tmp[4] = (short)f2bits(v1.x); tmp[5] = (short)f2bits(v1.y);
                tmp[6] = (short)f2bits(v1.z); tmp[7] = (short)f2bits(v1.w);
            } else {
                #pragma unroll
                for (int q = 0; q < 8; ++q) tmp[q] = 0;
            }
            *(us8*)&a_s[p * 2048 + t * 8] = *(us8*)&tmp[0];
        }
        __syncthreads();
        bf16x8 af[4], bg[4];
        #pragma unroll
        for (int i = 0; i < 4; ++i)
            af[i] = *(const bf16x8*)&a_s[(wr * 64 + i * 16 + fr) * 32 + l4 * 8];
        #pragma unroll
        for (int j = 0; j < 4; ++j)
            bg[j] = *(const bf16x8*)&b_s[(wc * 64 + j * 16 + fr) * 32 + l4 * 8];
        #pragma unroll
        for (int i = 0; i < 4; ++i)
            #pragma unroll
            for (int j = 0; j < 4; ++j)
                acc[i][j] = __builtin_amdgcn_mfma_f32_16x16x32_bf16(
                    af[i], bg[j], acc[i][j], 0, 0, 0);
    }
    // C/D layout: col = lane&15, row = (lane>>4)*4 + q
    #pragma unroll
    for (int i = 0; i < 4; ++i) {
        const int row0 = bm0 + wr * 64 + i * 16 + l4 * 4;
        #pragma unroll
        for (int j = 0; j < 4; ++j) {
            const int col = bn0 + wc * 64 + j * 16 + fr;
            #pragma unroll
            for (int q = 0; q < 4; ++q)
                lin[(long)(row0 + q) * 768 + col] = __float2bfloat16(acc[i][j][q]);
        }
    }
}

// ---------------------------------------------------------------------------
// Level MFMA GEMM: lin[rc,0:1280] = h_cat[p] @ Ut^T
// h_cat contiguous: compacted children adjacent -> row = h_child + cls*256.
// A and B both staged via global_load_lds width=16.
// ---------------------------------------------------------------------------
__global__ __launch_bounds__(256) void level_gemm_mfma(
    const bf16* __restrict__ h_child, const bf16* __restrict__ Ut,
    bf16* __restrict__ lin, const int lvl, const int p0, const int M)
{
    __shared__ __align__(16) short a_s[128 * 32];
    __shared__ __align__(16) short b_s[128 * 32];
    const int t    = threadIdx.x;
    const int bm0  = blockIdx.x * 128;
    const int bn0  = blockIdx.y * 128;
    const int lane = t & 63, wave = t >> 6;

    const int l4a = lane >> 2;
    const int k8  = (lane & 3) * 8;
    const bf16* aSrc[2];
    const bf16* bSrc[2];
    #pragma unroll
    for (int q = 0; q < 2; ++q) {
        const int n = wave * 2 + q;
        int p = p0 + bm0 + n * 16 + l4a;
        if (p >= M) p = M - 1;                  // clamp: reads safe, stores guarded
        const int tl  = p >> lvl;
        const int idx = p & ((1 << lvl) - 1);
        const int cls = tl * (2 << lvl) + 2 * idx;
        aSrc[q] = h_child + (long)cls * HS + k8;
        bSrc[q] = Ut + (long)(bn0 + n * 16 + l4a) * 512 + k8;
    }

    const int wr = wave >> 1, wc = wave & 1;
    const int fr = lane & 15, l4 = lane >> 4;

    f32x4 acc[4][4];
    #pragma unroll
    for (int i = 0; i < 4; ++i)
        #pragma unroll
        for (int j = 0; j < 4; ++j) acc[i][j] = (f32x4){0.f, 0.f, 0.f, 0.f};

    for (int kt = 0; kt < 512; kt += 32) {
        __syncthreads();
        #pragma unroll
        for (int q = 0; q < 2; ++q) {
            GLD16(aSrc[q] + kt, &a_s[(wave * 2 + q) * 512]);
            GLD16(bSrc[q] + kt, &b_s[(wave * 2 + q) * 512]);
        }
        __syncthreads();
        bf16x8 af[4], bg[4];
        #pragma unroll
        for (int i = 0; i < 4; ++i)
            af[i] = *(const bf16x8*)&a_s[(wr * 64 + i * 16 + fr) * 32 + l4 * 8];
        #pragma unroll
        for (int j = 0; j < 4; ++j)
            bg[j] = *(const bf16x8*)&b_s[(wc * 64 + j * 16 + fr) * 32 + l4 * 8];
        #pragma unroll
        for (int i = 0; i < 4; ++i)
            #pragma unroll
            for (int j = 0; j < 4; ++j)
                acc[i][j] = __builtin_amdgcn_mfma_f32_16x16x32_bf16(
                    af[i], bg[j], acc[i][j], 0, 0, 0);
    }
    #pragma unroll
    for (int i = 0; i < 4; ++i) {
        const int row0 = bm0 + wr * 64 + i * 16 + l4 * 4;
        #pragma unroll
        for (int j = 0; j < 4; ++j) {
            const int col = bn0 + wc * 64 + j * 16 + fr;
            #pragma unroll
            for (int q = 0; q < 4; ++q) {
                const int rr = row0 + q;
                if (p0 + rr < M)
                    lin[(long)rr * 1280 + col] = __float2bfloat16(acc[i][j][q]);
            }
        }
    }
}

// ---------------------------------------------------------------------------
// Fused per-node logits: out[node,0:4] = (h+mh) @ lin_w + lin_b
// ---------------------------------------------------------------------------
__device__ __forceinline__ void logits_reduce(
    float s, const float* __restrict__ lin_w, const float* __restrict__ lin_b,
    float* __restrict__ outp, int j)
{
    const float4 w = *(const float4*)(lin_w + j * 4);
    float p0 = s * w.x, p1 = s * w.y, p2 = s * w.z, p3 = s * w.w;
    #pragma unroll
    for (int off = 32; off > 0; off >>= 1) {
        p0 += __shfl_down(p0, off);
        p1 += __shfl_down(p1, off);
        p2 += __shfl_down(p2, off);
        p3 += __shfl_down(p3, off);
    }
    __shared__ float red[4][4];
    const int w_id = j >> 6, lane = j & 63;
    if (lane == 0) { red[w_id][0] = p0; red[w_id][1] = p1; red[w_id][2] = p2; red[w_id][3] = p3; }
    __syncthreads();
    if (j < 4) {
        outp[j] = red[0][j] + red[1][j] + red[2][j] + red[3][j] + lin_b[j];
    }
}

__global__ __launch_bounds__(256) void leaf_epi(
    const int* __restrict__ mask, const bf16* __restrict__ lin,
    const float* __restrict__ b_iou,
    const float* __restrict__ lin_w, const float* __restrict__ lin_b,
    bf16* __restrict__ h_s, bf16* __restrict__ c_s, bf16* __restrict__ mh_s,
    float* __restrict__ out, const int g0, const int s0)
{
    const int rc   = blockIdx.x;
    const int gr   = g0 + rc;
    const int tree = gr >> 9, idx = gr & 511;
    const int node = tree * NPT + 511 + idx;
    const int j    = threadIdx.x;
    const int m    = mask[node];
    const bf16* lr = lin + (long)rc * 768;

    const float pi = (m ? ld_bf(lr + j)       : 0.0f) + b_iou[j];
    const float po = (m ? ld_bf(lr + 256 + j) : 0.0f) + b_iou[256 + j];
    const float pu = (m ? ld_bf(lr + 512 + j) : 0.0f) + b_iou[512 + j];
    const float iv = sigm(pi), ov = sigm(po), uv = tanhf(pu);
    const float cv  = iv * uv;
    const float hv  = ov * tanhf(cv);
    const float mhv = fmaxf(hv, 0.0f);

    const long o = (long)(s0 + rc) * HS + j;
    h_s[o]  = __float2bfloat16(hv);
    c_s[o]  = __float2bfloat16(cv);
    mh_s[o] = __float2bfloat16(mhv);

    logits_reduce(hv + mhv, lin_w, lin_b, out + (long)node * 4, j);
}

__global__ __launch_bounds__(256) void level_epi(
    const bf16* __restrict__ lin,
    const float* __restrict__ b_iou, const float* __restrict__ U_f_b,
    const float* __restrict__ lin_w, const float* __restrict__ lin_b,
    const bf16* __restrict__ c_c, const bf16* __restrict__ mh_c,
    bf16* __restrict__ h_p, bf16* __restrict__ c_p, bf16* __restrict__ mh_p,
    float* __restrict__ out, const int lvl, const int p0, const int tree0)
{
    const int rc   = blockIdx.x;
    const int p    = p0 + rc;
    const int tl   = p >> lvl, idx = p & ((1 << lvl) - 1);
    const int node = (tree0 + tl) * NPT + (1 << lvl) - 1 + idx;
    const int cls  = tl * (2 << lvl) + 2 * idx;
    const int j    = threadIdx.x;
    const bf16* lr = lin + (long)rc * 1280;

    const float fl = sigm(ld_bf(lr + j)       + U_f_b[j]);
    const float fr = sigm(ld_bf(lr + 256 + j) + U_f_b[256 + j]);
    const float pi = ld_bf(lr + 512 + j)  + b_iou[j];
    const float po = ld_bf(lr + 768 + j)  + b_iou[256 + j];
    const float pu = ld_bf(lr + 1024 + j) + b_iou[512 + j];

    const float ccl = ld_bf(c_c  + (long)cls * HS + j);
    const float ccr = ld_bf(c_c  + (long)(cls + 1) * HS + j);
    const float mhl = ld_bf(mh_c + (long)cls * HS + j);
    const float mhr = ld_bf(mh_c + (long)(cls + 1) * HS + j);

    const float c_red  = fl * ccl + fr * ccr;
    const float mh_red = fmaxf(mhl, mhr);

    const float iv = sigm(pi), ov = sigm(po), uv = tanhf(pu);
    const float cv  = iv * uv + c_red;
    const float hv  = ov * tanhf(cv);
    const float mhv = fmaxf(hv, mh_red);

    const long o = (long)p * HS + j;
    h_p[o]  = __float2bfloat16(hv);
    c_p[o]  = __float2bfloat16(cv);
    mh_p[o] = __float2bfloat16(mhv);

    logits_reduce(hv + mhv, lin_w, lin_b, out + (long)node * 4, j);
}

// ---------------------------------------------------------------------------
extern "C" void kernel_launch(void* const* d_in, const int* in_sizes, int n_in,
                              void* d_out, int out_size, void* d_ws, size_t ws_size,
                              hipStream_t stream) {
    const int*   wordid = (const int*)d_in[0];
    const int*   mask   = (const int*)d_in[1];
    const float* emb    = (const float*)d_in[2];
    const float* W_iou  = (const float*)d_in[3];
    const float* U_iou  = (const float*)d_in[4];
    const float* U_f_w  = (const float*)d_in[5];
    const float* U_f_b  = (const float*)d_in[6];
    const float* b_iou  = (const float*)d_in[7];
    const float* lin_w  = (const float*)d_in[8];
    const float* lin_b  = (const float*)d_in[9];
    float* out = (float*)d_out;

    const size_t wElems   = (size_t)WT_ELEMS + UT_ELEMS;     // 851,968
    const size_t ws_elems = ws_size / 2;
    auto baseElems = [&](int T) -> size_t {
        return wElems + (size_t)T * 589824;  // states A(3x) + B(3x)
    };
    const size_t minLin = 128 * 1280;
    int T = 8;
    const int cands[4] = {128, 64, 32, 16};
    for (int ci = 0; ci < 4; ++ci) {
        if (baseElems(cands[ci]) + minLin <= ws_elems) { T = cands[ci]; break; }
    }
    const size_t linCap = ws_elems - baseElems(T);

    bf16* Wt = (bf16*)d_ws;
    bf16* Ut = Wt + WT_ELEMS;
    const size_t aR = (size_t)T * 512 * HS;
    const size_t bR = (size_t)T * 256 * HS;
    bf16* hA  = Ut  + UT_ELEMS;
    bf16* cA  = hA  + aR;
    bf16* mhA = cA  + aR;
    bf16* hB  = mhA + aR;
    bf16* cB  = hB  + bR;
    bf16* mhB = cB  + bR;
    bf16* lin = mhB + bR;

    prep_w<<<(int)((wElems + 255) / 256), 256, 0, stream>>>(
        W_iou, U_f_w, U_iou, Wt, Ut);

    // chunk-row capacities (multiples of 128, >=128 guaranteed by T choice)
    int CRl = (int)((linCap / 768) & ~(size_t)127);
    int CRv = (int)((linCap / 1280) & ~(size_t)127);
    if (CRl < 128) CRl = 128;
    if (CRv < 128) CRv = 128;

    for (int tree0 = 0; tree0 < NTREES; tree0 += T) {
        // ---- leaves -> A
        const int Ml = T * 512;
        for (int r0 = 0; r0 < Ml; r0 += CRl) {
            const int rows = (Ml - r0) < CRl ? (Ml - r0) : CRl;
            const int g0   = tree0 * 512 + r0;
            leaf_gemm_mfma<<<dim3(rows / 128, 6), 256, 0, stream>>>(
                wordid, mask, emb, Wt, lin, g0);
            leaf_epi<<<rows, 256, 0, stream>>>(
                mask, lin, b_iou, lin_w, lin_b, hA, cA, mhA, out, g0, r0);
        }
        // ---- internal levels, bottom-up; ping-pong A<->B
        bool childIsA = true;
        for (int l = 8; l >= 0; --l) {
            bf16 *hc, *cc, *mc, *hp, *cp, *mp;
            if (childIsA) { hc = hA; cc = cA; mc = mhA; hp = hB; cp = cB; mp = mhB; }
            else          { hc = hB; cc = cB; mc = mhB; hp = hA; cp = cA; mp = mhA; }
            const int M = T << l;
            for (int p0 = 0; p0 < M; p0 += CRv) {
                const int rows = (M - p0) < CRv ? (M - p0) : CRv;
                level_gemm_mfma<<<dim3((rows + 127) / 128, 10), 256, 0, stream>>>(
                    hc, Ut, lin, l, p0, M);
                level_epi<<<rows, 256, 0, stream>>>(
                    lin, b_iou, U_f_b, lin_w, lin_b, cc, mc, hp, cp, mp,
                    out, l, p0, tree0);
            }
            childIsA = !childIsA;
        }
    }
}

// Round 5
// 461.084 us; speedup vs baseline: 3.8331x; 1.1340x over previous
//
#include <hip/hip_runtime.h>
#include <hip/hip_bf16.h>

// TreeLSTM, 128 perfect binary trees, depth 9, H=256. N=130944 nodes.
//
//   - iou0=(x@W_iou)*mask only consumed at LEAVES -> leaf-only W_iou GEMM.
//   - States compacted per level, ping-pong A/B buffers; trees slabbed by T
//     chosen from ws_size (T=128 + unchunked lin fits in 256 MiB).
//   - GEMMs: bf16 MFMA (16x16x32), m97 structure: 128x128 tile, BK=32,
//     4 waves (2x2), LINEAR [128][32] LDS tiles, global_load_lds width=16.
//   - Epilogues: wave-per-row (4 rows / 256-thr block), no __syncthreads,
//     ushort4 bf16 vector loads, fast exp/rcp gates, wave-shfl logits reduce.
//   - Weights pre-transposed to bf16: Wt[768][256], Ut[1280][512].

#define NTREES 128
#define NPT    1023
#define HS     256

typedef __hip_bfloat16 bf16;
typedef unsigned short us8 __attribute__((ext_vector_type(8)));
typedef unsigned short us4 __attribute__((ext_vector_type(4)));
typedef short bf16x8 __attribute__((ext_vector_type(8)));
typedef float f32x4 __attribute__((ext_vector_type(4)));

typedef __attribute__((address_space(1))) const void gvoid;
typedef __attribute__((address_space(3))) void svoid;
#define GLD16(gp, lp) \
    __builtin_amdgcn_global_load_lds((gvoid*)(gp), (svoid*)(lp), 16, 0, 0)

__device__ __forceinline__ float bits2f(unsigned short b) {
    return __uint_as_float(((unsigned)b) << 16);
}
__device__ __forceinline__ unsigned short f2bits(float x) {
    bf16 h = __float2bfloat16(x);
    return *reinterpret_cast<unsigned short*>(&h);
}
// Fast gates: v_exp_f32 + v_rcp_f32 (quarter-rate HW units, ~1ulp rcp).
__device__ __forceinline__ float fsigm(float x) {
    return __builtin_amdgcn_rcpf(1.0f + __expf(-x));
}
__device__ __forceinline__ float ftanh(float x) {
    // (e^2x-1)/(e^2x+1) = 1 - 2/(e^2x+1); saturates correctly at +-inf.
    return 1.0f - 2.0f * __builtin_amdgcn_rcpf(1.0f + __expf(2.0f * x));
}

// ---------------------------------------------------------------------------
// Weight prep: Wt[n][k] = W_iou[k][n] (768x256), Ut[n][k] = cat(U_f_w,U_iou)^T
// ---------------------------------------------------------------------------
#define WT_ELEMS (768 * 256)
#define UT_ELEMS (1280 * 512)

__global__ __launch_bounds__(256) void prep_w(
    const float* __restrict__ W_iou, const float* __restrict__ U_f_w,
    const float* __restrict__ U_iou, bf16* __restrict__ Wt, bf16* __restrict__ Ut)
{
    const int i = blockIdx.x * 256 + threadIdx.x;
    if (i < WT_ELEMS) {
        const int n = i >> 8, k = i & 255;
        Wt[i] = __float2bfloat16(W_iou[k * 768 + n]);
    } else if (i < WT_ELEMS + UT_ELEMS) {
        const int j = i - WT_ELEMS;
        const int n = j >> 9, k = j & 511;
        const float v = (n < 512) ? U_f_w[k * 512 + n] : U_iou[k * 768 + (n - 512)];
        Ut[j] = __float2bfloat16(v);
    }
}

// ---------------------------------------------------------------------------
// Leaf MFMA GEMM: lin[rc,0:768] = bf16(emb[wordid[node]]) @ Wt^T  (0 if !mask)
// ---------------------------------------------------------------------------
__global__ __launch_bounds__(256) void leaf_gemm_mfma(
    const int* __restrict__ wordid, const int* __restrict__ mask,
    const float* __restrict__ emb, const bf16* __restrict__ Wt,
    bf16* __restrict__ lin, const int g0)
{
    __shared__ __align__(16) short a_s[128 * 32];
    __shared__ __align__(16) short b_s[128 * 32];
    const int t    = threadIdx.x;
    const int bm0  = blockIdx.x * 128;
    const int bn0  = blockIdx.y * 128;
    const int lane = t & 63, wave = t >> 6;

    const int arow_lo = t >> 2;          // 0..63
    const int k8t     = (t & 3) * 8;
    const float* aptr[2];
    int amask[2];
    #pragma unroll
    for (int p = 0; p < 2; ++p) {
        const int row  = p * 64 + arow_lo;
        const int gr   = g0 + bm0 + row;
        const int tree = gr >> 9, idx = gr & 511;
        const int node = tree * NPT + 511 + idx;
        amask[p] = mask[node];
        aptr[p]  = emb + (long)wordid[node] * HS + k8t;
    }

    const int l4a = lane >> 2;
    const int k8  = (lane & 3) * 8;
    const bf16* bSrc[2];
    #pragma unroll
    for (int q = 0; q < 2; ++q) {
        const int n = wave * 2 + q;
        bSrc[q] = Wt + (long)(bn0 + n * 16 + l4a) * 256 + k8;
    }

    const int wr = wave >> 1, wc = wave & 1;
    const int fr = lane & 15, l4 = lane >> 4;

    f32x4 acc[4][4];
    #pragma unroll
    for (int i = 0; i < 4; ++i)
        #pragma unroll
        for (int j = 0; j < 4; ++j) acc[i][j] = (f32x4){0.f, 0.f, 0.f, 0.f};

    for (int kt = 0; kt < 256; kt += 32) {
        __syncthreads();
        #pragma unroll
        for (int q = 0; q < 2; ++q)
            GLD16(bSrc[q] + kt, &b_s[(wave * 2 + q) * 512]);
        #pragma unroll
        for (int p = 0; p < 2; ++p) {
            short tmp[8];
            if (amask[p]) {
                const float4 v0 = *(const float4*)(aptr[p] + kt);
                const float4 v1 = *(const float4*)(aptr[p] + kt + 4);
                tmp[0] = (short)f2bits(v0.x); tmp[1] = (short)f2bits(v0.y);
                tmp[2] = (short)f2bits(v0.z); tmp[3] = (short)f2bits(v0.w);
                tmp[4] = (short)f2bits(v1.x); tmp[5] = (short)f2bits(v1.y);
                tmp[6] = (short)f2bits(v1.z); tmp[7] = (short)f2bits(v1.w);
            } else {
                #pragma unroll
                for (int q = 0; q < 8; ++q) tmp[q] = 0;
            }
            *(us8*)&a_s[p * 2048 + t * 8] = *(us8*)&tmp[0];
        }
        __syncthreads();
        bf16x8 af[4], bg[4];
        #pragma unroll
        for (int i = 0; i < 4; ++i)
            af[i] = *(const bf16x8*)&a_s[(wr * 64 + i * 16 + fr) * 32 + l4 * 8];
        #pragma unroll
        for (int j = 0; j < 4; ++j)
            bg[j] = *(const bf16x8*)&b_s[(wc * 64 + j * 16 + fr) * 32 + l4 * 8];
        #pragma unroll
        for (int i = 0; i < 4; ++i)
            #pragma unroll
            for (int j = 0; j < 4; ++j)
                acc[i][j] = __builtin_amdgcn_mfma_f32_16x16x32_bf16(
                    af[i], bg[j], acc[i][j], 0, 0, 0);
    }
    #pragma unroll
    for (int i = 0; i < 4; ++i) {
        const int row0 = bm0 + wr * 64 + i * 16 + l4 * 4;
        #pragma unroll
        for (int j = 0; j < 4; ++j) {
            const int col = bn0 + wc * 64 + j * 16 + fr;
            #pragma unroll
            for (int q = 0; q < 4; ++q)
                lin[(long)(row0 + q) * 768 + col] = __float2bfloat16(acc[i][j][q]);
        }
    }
}

// ---------------------------------------------------------------------------
// Level MFMA GEMM: lin[rc,0:1280] = h_cat[p] @ Ut^T
// ---------------------------------------------------------------------------
__global__ __launch_bounds__(256) void level_gemm_mfma(
    const bf16* __restrict__ h_child, const bf16* __restrict__ Ut,
    bf16* __restrict__ lin, const int lvl, const int p0, const int M)
{
    __shared__ __align__(16) short a_s[128 * 32];
    __shared__ __align__(16) short b_s[128 * 32];
    const int t    = threadIdx.x;
    const int bm0  = blockIdx.x * 128;
    const int bn0  = blockIdx.y * 128;
    const int lane = t & 63, wave = t >> 6;

    const int l4a = lane >> 2;
    const int k8  = (lane & 3) * 8;
    const bf16* aSrc[2];
    const bf16* bSrc[2];
    #pragma unroll
    for (int q = 0; q < 2; ++q) {
        const int n = wave * 2 + q;
        int p = p0 + bm0 + n * 16 + l4a;
        if (p >= M) p = M - 1;
        const int tl  = p >> lvl;
        const int idx = p & ((1 << lvl) - 1);
        const int cls = tl * (2 << lvl) + 2 * idx;
        aSrc[q] = h_child + (long)cls * HS + k8;
        bSrc[q] = Ut + (long)(bn0 + n * 16 + l4a) * 512 + k8;
    }

    const int wr = wave >> 1, wc = wave & 1;
    const int fr = lane & 15, l4 = lane >> 4;

    f32x4 acc[4][4];
    #pragma unroll
    for (int i = 0; i < 4; ++i)
        #pragma unroll
        for (int j = 0; j < 4; ++j) acc[i][j] = (f32x4){0.f, 0.f, 0.f, 0.f};

    for (int kt = 0; kt < 512; kt += 32) {
        __syncthreads();
        #pragma unroll
        for (int q = 0; q < 2; ++q) {
            GLD16(aSrc[q] + kt, &a_s[(wave * 2 + q) * 512]);
            GLD16(bSrc[q] + kt, &b_s[(wave * 2 + q) * 512]);
        }
        __syncthreads();
        bf16x8 af[4], bg[4];
        #pragma unroll
        for (int i = 0; i < 4; ++i)
            af[i] = *(const bf16x8*)&a_s[(wr * 64 + i * 16 + fr) * 32 + l4 * 8];
        #pragma unroll
        for (int j = 0; j < 4; ++j)
            bg[j] = *(const bf16x8*)&b_s[(wc * 64 + j * 16 + fr) * 32 + l4 * 8];
        #pragma unroll
        for (int i = 0; i < 4; ++i)
            #pragma unroll
            for (int j = 0; j < 4; ++j)
                acc[i][j] = __builtin_amdgcn_mfma_f32_16x16x32_bf16(
                    af[i], bg[j], acc[i][j], 0, 0, 0);
    }
    #pragma unroll
    for (int i = 0; i < 4; ++i) {
        const int row0 = bm0 + wr * 64 + i * 16 + l4 * 4;
        #pragma unroll
        for (int j = 0; j < 4; ++j) {
            const int col = bn0 + wc * 64 + j * 16 + fr;
            #pragma unroll
            for (int q = 0; q < 4; ++q) {
                const int rr = row0 + q;
                if (p0 + rr < M)
                    lin[(long)rr * 1280 + col] = __float2bfloat16(acc[i][j][q]);
            }
        }
    }
}

// ---------------------------------------------------------------------------
// Epilogues: wave-per-row. Lane owns elems 4*lane..4*lane+3. No __syncthreads.
// Logits: p_c = sum_j (h_j+mh_j)*lin_w[j][c]; wave shfl_xor reduce; lane 0 st.
// ---------------------------------------------------------------------------
__global__ __launch_bounds__(256) void leaf_epi(
    const int* __restrict__ mask, const bf16* __restrict__ lin,
    const float* __restrict__ b_iou,
    const float* __restrict__ lin_w, const float* __restrict__ lin_b,
    bf16* __restrict__ h_s, bf16* __restrict__ c_s, bf16* __restrict__ mh_s,
    float* __restrict__ out, const int g0, const int s0, const int rows)
{
    const int wave = threadIdx.x >> 6, lane = threadIdx.x & 63;
    const int rc   = blockIdx.x * 4 + wave;
    if (rc >= rows) return;
    const int gr   = g0 + rc;
    const int tree = gr >> 9, idx = gr & 511;
    const int node = tree * NPT + 511 + idx;
    const float msk = mask[node] ? 1.0f : 0.0f;
    const int j0   = lane * 4;

    const bf16* lr = lin + (long)rc * 768 + j0;
    const us4 vi = *(const us4*)(lr);
    const us4 vo = *(const us4*)(lr + 256);
    const us4 vu = *(const us4*)(lr + 512);
    const float4 bi = *(const float4*)(b_iou + j0);
    const float4 bo = *(const float4*)(b_iou + 256 + j0);
    const float4 bu = *(const float4*)(b_iou + 512 + j0);

    us4 sh, sc, sm;
    float p0 = 0.f, p1 = 0.f, p2 = 0.f, p3 = 0.f;
    #pragma unroll
    for (int q = 0; q < 4; ++q) {
        const float pi = msk * bits2f(vi[q]) + ((const float*)&bi)[q];
        const float po = msk * bits2f(vo[q]) + ((const float*)&bo)[q];
        const float pu = msk * bits2f(vu[q]) + ((const float*)&bu)[q];
        const float iv = fsigm(pi), ov = fsigm(po), uv = ftanh(pu);
        const float cv  = iv * uv;
        const float hv  = ov * ftanh(cv);
        const float mhv = fmaxf(hv, 0.0f);
        sh[q] = f2bits(hv); sc[q] = f2bits(cv); sm[q] = f2bits(mhv);
        const float s = hv + mhv;
        const float4 w = *(const float4*)(lin_w + (j0 + q) * 4);
        p0 += s * w.x; p1 += s * w.y; p2 += s * w.z; p3 += s * w.w;
    }
    const long o = (long)(s0 + rc) * HS + j0;
    *(us4*)(h_s + o)  = sh;
    *(us4*)(c_s + o)  = sc;
    *(us4*)(mh_s + o) = sm;

    #pragma unroll
    for (int m = 1; m < 64; m <<= 1) {
        p0 += __shfl_xor(p0, m); p1 += __shfl_xor(p1, m);
        p2 += __shfl_xor(p2, m); p3 += __shfl_xor(p3, m);
    }
    if (lane == 0) {
        float4 r;
        r.x = p0 + lin_b[0]; r.y = p1 + lin_b[1];
        r.z = p2 + lin_b[2]; r.w = p3 + lin_b[3];
        *(float4*)(out + (long)node * 4) = r;
    }
}

__global__ __launch_bounds__(256) void level_epi(
    const bf16* __restrict__ lin,
    const float* __restrict__ b_iou, const float* __restrict__ U_f_b,
    const float* __restrict__ lin_w, const float* __restrict__ lin_b,
    const bf16* __restrict__ c_c, const bf16* __restrict__ mh_c,
    bf16* __restrict__ h_p, bf16* __restrict__ c_p, bf16* __restrict__ mh_p,
    float* __restrict__ out, const int lvl, const int p0r, const int tree0,
    const int rows)
{
    const int wave = threadIdx.x >> 6, lane = threadIdx.x & 63;
    const int rc   = blockIdx.x * 4 + wave;
    if (rc >= rows) return;
    const int p    = p0r + rc;
    const int tl   = p >> lvl, idx = p & ((1 << lvl) - 1);
    const int node = (tree0 + tl) * NPT + (1 << lvl) - 1 + idx;
    const int cls  = tl * (2 << lvl) + 2 * idx;
    const int j0   = lane * 4;

    const bf16* lr = lin + (long)rc * 1280 + j0;
    const us4 vfl = *(const us4*)(lr);
    const us4 vfr = *(const us4*)(lr + 256);
    const us4 vi  = *(const us4*)(lr + 512);
    const us4 vo  = *(const us4*)(lr + 768);
    const us4 vu  = *(const us4*)(lr + 1024);
    const us4 vcl = *(const us4*)(c_c  + (long)cls * HS + j0);
    const us4 vcr = *(const us4*)(c_c  + (long)(cls + 1) * HS + j0);
    const us4 vml = *(const us4*)(mh_c + (long)cls * HS + j0);
    const us4 vmr = *(const us4*)(mh_c + (long)(cls + 1) * HS + j0);
    const float4 ufl = *(const float4*)(U_f_b + j0);
    const float4 ufr = *(const float4*)(U_f_b + 256 + j0);
    const float4 bi  = *(const float4*)(b_iou + j0);
    const float4 bo  = *(const float4*)(b_iou + 256 + j0);
    const float4 bu  = *(const float4*)(b_iou + 512 + j0);

    us4 sh, sc, sm;
    float p0 = 0.f, p1 = 0.f, p2 = 0.f, p3 = 0.f;
    #pragma unroll
    for (int q = 0; q < 4; ++q) {
        const float fl = fsigm(bits2f(vfl[q]) + ((const float*)&ufl)[q]);
        const float fr = fsigm(bits2f(vfr[q]) + ((const float*)&ufr)[q]);
        const float pi = bits2f(vi[q]) + ((const float*)&bi)[q];
        const float po = bits2f(vo[q]) + ((const float*)&bo)[q];
        const float pu = bits2f(vu[q]) + ((const float*)&bu)[q];
        const float c_red  = fl * bits2f(vcl[q]) + fr * bits2f(vcr[q]);
        const float mh_red = fmaxf(bits2f(vml[q]), bits2f(vmr[q]));
        const float iv = fsigm(pi), ov = fsigm(po), uv = ftanh(pu);
        const float cv  = iv * uv + c_red;
        const float hv  = ov * ftanh(cv);
        const float mhv = fmaxf(hv, mh_red);
        sh[q] = f2bits(hv); sc[q] = f2bits(cv); sm[q] = f2bits(mhv);
        const float s = hv + mhv;
        const float4 w = *(const float4*)(lin_w + (j0 + q) * 4);
        p0 += s * w.x; p1 += s * w.y; p2 += s * w.z; p3 += s * w.w;
    }
    const long o = (long)p * HS + j0;
    *(us4*)(h_p + o)  = sh;
    *(us4*)(c_p + o)  = sc;
    *(us4*)(mh_p + o) = sm;

    #pragma unroll
    for (int m = 1; m < 64; m <<= 1) {
        p0 += __shfl_xor(p0, m); p1 += __shfl_xor(p1, m);
        p2 += __shfl_xor(p2, m); p3 += __shfl_xor(p3, m);
    }
    if (lane == 0) {
        float4 r;
        r.x = p0 + lin_b[0]; r.y = p1 + lin_b[1];
        r.z = p2 + lin_b[2]; r.w = p3 + lin_b[3];
        *(float4*)(out + (long)node * 4) = r;
    }
}

// ---------------------------------------------------------------------------
extern "C" void kernel_launch(void* const* d_in, const int* in_sizes, int n_in,
                              void* d_out, int out_size, void* d_ws, size_t ws_size,
                              hipStream_t stream) {
    const int*   wordid = (const int*)d_in[0];
    const int*   mask   = (const int*)d_in[1];
    const float* emb    = (const float*)d_in[2];
    const float* W_iou  = (const float*)d_in[3];
    const float* U_iou  = (const float*)d_in[4];
    const float* U_f_w  = (const float*)d_in[5];
    const float* U_f_b  = (const float*)d_in[6];
    const float* b_iou  = (const float*)d_in[7];
    const float* lin_w  = (const float*)d_in[8];
    const float* lin_b  = (const float*)d_in[9];
    float* out = (float*)d_out;

    const size_t wElems   = (size_t)WT_ELEMS + UT_ELEMS;     // 851,968
    const size_t ws_elems = ws_size / 2;
    auto baseElems = [&](int T) -> size_t {
        return wElems + (size_t)T * 589824;  // states A(3x) + B(3x)
    };
    const size_t minLin = 128 * 1280;
    int T = 8;
    const int cands[4] = {128, 64, 32, 16};
    for (int ci = 0; ci < 4; ++ci) {
        if (baseElems(cands[ci]) + minLin <= ws_elems) { T = cands[ci]; break; }
    }
    const size_t linCap = ws_elems - baseElems(T);

    bf16* Wt = (bf16*)d_ws;
    bf16* Ut = Wt + WT_ELEMS;
    const size_t aR = (size_t)T * 512 * HS;
    const size_t bR = (size_t)T * 256 * HS;
    bf16* hA  = Ut  + UT_ELEMS;
    bf16* cA  = hA  + aR;
    bf16* mhA = cA  + aR;
    bf16* hB  = mhA + aR;
    bf16* cB  = hB  + bR;
    bf16* mhB = cB  + bR;
    bf16* lin = mhB + bR;

    prep_w<<<(int)((wElems + 255) / 256), 256, 0, stream>>>(
        W_iou, U_f_w, U_iou, Wt, Ut);

    int CRl = (int)((linCap / 768) & ~(size_t)127);
    int CRv = (int)((linCap / 1280) & ~(size_t)127);
    if (CRl < 128) CRl = 128;
    if (CRv < 128) CRv = 128;

    for (int tree0 = 0; tree0 < NTREES; tree0 += T) {
        // ---- leaves -> A
        const int Ml = T * 512;
        for (int r0 = 0; r0 < Ml; r0 += CRl) {
            const int rows = (Ml - r0) < CRl ? (Ml - r0) : CRl;
            const int g0   = tree0 * 512 + r0;
            leaf_gemm_mfma<<<dim3(rows / 128, 6), 256, 0, stream>>>(
                wordid, mask, emb, Wt, lin, g0);
            leaf_epi<<<(rows + 3) / 4, 256, 0, stream>>>(
                mask, lin, b_iou, lin_w, lin_b, hA, cA, mhA, out, g0, r0, rows);
        }
        // ---- internal levels, bottom-up; ping-pong A<->B
        bool childIsA = true;
        for (int l = 8; l >= 0; --l) {
            bf16 *hc, *cc, *mc, *hp, *cp, *mp;
            if (childIsA) { hc = hA; cc = cA; mc = mhA; hp = hB; cp = cB; mp = mhB; }
            else          { hc = hB; cc = cB; mc = mhB; hp = hA; cp = cA; mp = mhA; }
            const int M = T << l;
            for (int p0 = 0; p0 < M; p0 += CRv) {
                const int rows = (M - p0) < CRv ? (M - p0) : CRv;
                level_gemm_mfma<<<dim3((rows + 127) / 128, 10), 256, 0, stream>>>(
                    hc, Ut, lin, l, p0, M);
                level_epi<<<(rows + 3) / 4, 256, 0, stream>>>(
                    lin, b_iou, U_f_b, lin_w, lin_b, cc, mc, hp, cp, mp,
                    out, l, p0, tree0, rows);
            }
            childIsA = !childIsA;
        }
    }
}

// Round 6
// 453.650 us; speedup vs baseline: 3.8959x; 1.0164x over previous
//
#include <hip/hip_runtime.h>
#include <hip/hip_bf16.h>

// TreeLSTM, 128 perfect binary trees, depth 9, H=256. N=130944 nodes.
//
// R5: GEMM+epilogue FUSION. Column tile = 32 j's replicated across the gate
// strips (5 for levels: fl|fr|i|o|u at n=g*256+j; 3 for leaves: i|o|u).
// MFMA C/D layout (col=lane&15) => all gates of one j land in the SAME lane
// => epilogue (gates, child c/mh reduce, h/c/mh stores) is lane-local.
// lin intermediate eliminated. Logits deferred: s=h+mh stored to full-N
// bf16 array; one memory-bound logits pass at the end.
//
// ws (bf16): Wt[768*256], Ut[1280*512], s_full[N*256],
//            hA,cA,mhA [T*512*256], hB,cB,mhB [T*256*256]   (T=128: 220 MB)

#define NTREES 128
#define NPT    1023
#define HS     256
#define NNODES (NTREES * NPT)

typedef __hip_bfloat16 bf16;
typedef unsigned short us8 __attribute__((ext_vector_type(8)));
typedef unsigned short us4 __attribute__((ext_vector_type(4)));
typedef short bf16x8 __attribute__((ext_vector_type(8)));
typedef float f32x4 __attribute__((ext_vector_type(4)));

typedef __attribute__((address_space(1))) const void gvoid;
typedef __attribute__((address_space(3))) void svoid;
#define GLD16(gp, lp) \
    __builtin_amdgcn_global_load_lds((gvoid*)(gp), (svoid*)(lp), 16, 0, 0)

__device__ __forceinline__ float bits2f(unsigned short b) {
    return __uint_as_float(((unsigned)b) << 16);
}
__device__ __forceinline__ float ld_bf(const bf16* p) {
    return bits2f(*reinterpret_cast<const unsigned short*>(p));
}
__device__ __forceinline__ unsigned short f2bits(float x) {
    bf16 h = __float2bfloat16(x);
    return *reinterpret_cast<unsigned short*>(&h);
}
__device__ __forceinline__ float fsigm(float x) {
    return __builtin_amdgcn_rcpf(1.0f + __expf(-x));
}
__device__ __forceinline__ float ftanh(float x) {
    return 1.0f - 2.0f * __builtin_amdgcn_rcpf(1.0f + __expf(2.0f * x));
}

// ---------------------------------------------------------------------------
#define WT_ELEMS (768 * 256)
#define UT_ELEMS (1280 * 512)

__global__ __launch_bounds__(256) void prep_w(
    const float* __restrict__ W_iou, const float* __restrict__ U_f_w,
    const float* __restrict__ U_iou, bf16* __restrict__ Wt, bf16* __restrict__ Ut)
{
    const int i = blockIdx.x * 256 + threadIdx.x;
    if (i < WT_ELEMS) {
        const int n = i >> 8, k = i & 255;
        Wt[i] = __float2bfloat16(W_iou[k * 768 + n]);
    } else if (i < WT_ELEMS + UT_ELEMS) {
        const int j = i - WT_ELEMS;
        const int n = j >> 9, k = j & 511;
        const float v = (n < 512) ? U_f_w[k * 512 + n] : U_iou[k * 768 + (n - 512)];
        Ut[j] = __float2bfloat16(v);
    }
}

// ---------------------------------------------------------------------------
// Fused leaf: iou = (emb[wordid]@W_iou)*mask (via zeroed A rows), gates,
// h/c/mh stores (compacted slab rows), s=h+mh to s_full. Tile 128 x (32j x 3g).
// ---------------------------------------------------------------------------
__global__ __launch_bounds__(256) void leaf_fused(
    const int* __restrict__ wordid, const int* __restrict__ mask,
    const float* __restrict__ emb, const bf16* __restrict__ Wt,
    const float* __restrict__ b_iou,
    bf16* __restrict__ h_s, bf16* __restrict__ c_s, bf16* __restrict__ mh_s,
    bf16* __restrict__ s_full, const int tree0)
{
    __shared__ __align__(16) short a_s[128 * 32];
    __shared__ __align__(16) short b_s[96 * 32];
    const int t    = threadIdx.x;
    const int bm0  = blockIdx.x * 128;
    const int c0   = blockIdx.y * 32;
    const int lane = t & 63, wave = t >> 6;

    // A register staging: 2 passes, row = p*64 + t/4, 8 shorts at (t%4)*8
    const int k8t = (t & 3) * 8;
    const float* aptr[2];
    int amask[2];
    #pragma unroll
    for (int p = 0; p < 2; ++p) {
        const int row  = p * 64 + (t >> 2);
        const int gr   = tree0 * 512 + bm0 + row;
        const int node = (gr >> 9) * NPT + 511 + (gr & 511);
        amask[p] = mask[node];
        aptr[p]  = emb + (long)wordid[node] * HS + k8t;
    }

    // B global_load_lds: 96 rows -> 6 instrs; waves 0..2 take 2 each.
    const int l4a = lane >> 2, k8 = (lane & 3) * 8;
    const int bCnt = (wave < 3) ? 2 : 0;
    const int bStart = wave * 2;
    const bf16* bSrc[2];
    #pragma unroll
    for (int q = 0; q < 2; ++q) {
        int rb = (bStart + q) * 16 + l4a;
        if (rb > 95) rb = 95;                    // wave3: ptr unused
        const int g = rb >> 5, jl = rb & 31;
        bSrc[q] = Wt + (long)(g * 256 + c0 + jl) * 256 + k8;
    }

    const int wr = wave >> 1, wc = wave & 1;
    const int fr = lane & 15, l4 = lane >> 4;

    f32x4 acc[4][3];
    #pragma unroll
    for (int i = 0; i < 4; ++i)
        #pragma unroll
        for (int g = 0; g < 3; ++g) acc[i][g] = (f32x4){0.f, 0.f, 0.f, 0.f};

    for (int kt = 0; kt < 256; kt += 32) {
        __syncthreads();
        #pragma unroll
        for (int q = 0; q < 2; ++q)
            if (q < bCnt) GLD16(bSrc[q] + kt, &b_s[(bStart + q) * 512]);
        #pragma unroll
        for (int p = 0; p < 2; ++p) {
            short tmp[8];
            if (amask[p]) {
                const float4 v0 = *(const float4*)(aptr[p] + kt);
                const float4 v1 = *(const float4*)(aptr[p] + kt + 4);
                tmp[0] = (short)f2bits(v0.x); tmp[1] = (short)f2bits(v0.y);
                tmp[2] = (short)f2bits(v0.z); tmp[3] = (short)f2bits(v0.w);
                tmp[4] = (short)f2bits(v1.x); tmp[5] = (short)f2bits(v1.y);
                tmp[6] = (short)f2bits(v1.z); tmp[7] = (short)f2bits(v1.w);
            } else {
                #pragma unroll
                for (int q = 0; q < 8; ++q) tmp[q] = 0;
            }
            *(us8*)&a_s[p * 2048 + t * 8] = *(us8*)&tmp[0];
        }
        __syncthreads();
        bf16x8 af[4], bg[3];
        #pragma unroll
        for (int i = 0; i < 4; ++i)
            af[i] = *(const bf16x8*)&a_s[(wr * 64 + i * 16 + fr) * 32 + l4 * 8];
        #pragma unroll
        for (int g = 0; g < 3; ++g)
            bg[g] = *(const bf16x8*)&b_s[(g * 32 + wc * 16 + fr) * 32 + l4 * 8];
        #pragma unroll
        for (int i = 0; i < 4; ++i)
            #pragma unroll
            for (int g = 0; g < 3; ++g)
                acc[i][g] = __builtin_amdgcn_mfma_f32_16x16x32_bf16(
                    af[i], bg[g], acc[i][g], 0, 0, 0);
    }

    // Fused epilogue: lane owns j for all gates; 16 rows per lane.
    const int j  = c0 + wc * 16 + fr;
    const float bi = b_iou[j], bo = b_iou[256 + j], bu = b_iou[512 + j];
    #pragma unroll
    for (int i = 0; i < 4; ++i) {
        #pragma unroll
        for (int q = 0; q < 4; ++q) {
            const int r    = bm0 + wr * 64 + i * 16 + l4 * 4 + q;  // slab row
            const int gr   = tree0 * 512 + r;
            const int node = (gr >> 9) * NPT + 511 + (gr & 511);
            const float iv = fsigm(acc[i][0][q] + bi);
            const float ov = fsigm(acc[i][1][q] + bo);
            const float uv = ftanh(acc[i][2][q] + bu);
            const float cv  = iv * uv;
            const float hv  = ov * ftanh(cv);
            const float mhv = fmaxf(hv, 0.0f);
            const long o = (long)r * HS + j;
            h_s[o]  = __float2bfloat16(hv);
            c_s[o]  = __float2bfloat16(cv);
            mh_s[o] = __float2bfloat16(mhv);
            s_full[(long)node * HS + j] = __float2bfloat16(hv + mhv);
        }
    }
}

// ---------------------------------------------------------------------------
// Fused level: iou/f = h_cat@[U_f_w|U_iou], gates, child c/mh reduce, stores.
// Tile 128 x (32j x 5g). h_cat row contiguous (children adjacent compacted).
// ---------------------------------------------------------------------------
__global__ __launch_bounds__(256) void level_fused(
    const bf16* __restrict__ h_child, const bf16* __restrict__ c_c,
    const bf16* __restrict__ mh_c, const bf16* __restrict__ Ut,
    const float* __restrict__ U_f_b, const float* __restrict__ b_iou,
    bf16* __restrict__ h_p, bf16* __restrict__ c_p, bf16* __restrict__ mh_p,
    bf16* __restrict__ s_full, const int lvl, const int M, const int tree0)
{
    __shared__ __align__(16) short a_s[128 * 32];
    __shared__ __align__(16) short b_s[160 * 32];
    const int t    = threadIdx.x;
    const int bm0  = blockIdx.x * 128;
    const int c0   = blockIdx.y * 32;
    const int lane = t & 63, wave = t >> 6;

    const int l4a = lane >> 2, k8 = (lane & 3) * 8;

    // A: 128 rows -> 8 instrs, 2 per wave. Row r -> parent p -> child pair.
    const bf16* aSrc[2];
    #pragma unroll
    for (int q = 0; q < 2; ++q) {
        int p = bm0 + wave * 32 + q * 16 + l4a;
        if (p >= M) p = M - 1;                   // clamp reads; stores guarded
        const int tl  = p >> lvl;
        const int idx = p & ((1 << lvl) - 1);
        const int cls = tl * (2 << lvl) + 2 * idx;
        aSrc[q] = h_child + (long)cls * HS + k8; // 512 contiguous (2 children)
    }
    // B: 160 rows -> 10 instrs; waves {3,3,2,2}.
    const int bCnt   = (wave < 2) ? 3 : 2;
    const int bStart = (wave < 2) ? wave * 3 : 6 + (wave - 2) * 2;
    const bf16* bSrc[3];
    #pragma unroll
    for (int q = 0; q < 3; ++q) {
        int rb = (bStart + q) * 16 + l4a;
        if (rb > 159) rb = 159;
        const int g = rb >> 5, jl = rb & 31;
        bSrc[q] = Ut + (long)(g * 256 + c0 + jl) * 512 + k8;
    }

    const int wr = wave >> 1, wc = wave & 1;
    const int fr = lane & 15, l4 = lane >> 4;

    f32x4 acc[4][5];
    #pragma unroll
    for (int i = 0; i < 4; ++i)
        #pragma unroll
        for (int g = 0; g < 5; ++g) acc[i][g] = (f32x4){0.f, 0.f, 0.f, 0.f};

    for (int kt = 0; kt < 512; kt += 32) {
        __syncthreads();
        #pragma unroll
        for (int q = 0; q < 2; ++q)
            GLD16(aSrc[q] + kt, &a_s[(wave * 2 + q) * 512]);
        #pragma unroll
        for (int q = 0; q < 3; ++q)
            if (q < bCnt) GLD16(bSrc[q] + kt, &b_s[(bStart + q) * 512]);
        __syncthreads();
        bf16x8 af[4], bg[5];
        #pragma unroll
        for (int i = 0; i < 4; ++i)
            af[i] = *(const bf16x8*)&a_s[(wr * 64 + i * 16 + fr) * 32 + l4 * 8];
        #pragma unroll
        for (int g = 0; g < 5; ++g)
            bg[g] = *(const bf16x8*)&b_s[(g * 32 + wc * 16 + fr) * 32 + l4 * 8];
        #pragma unroll
        for (int i = 0; i < 4; ++i)
            #pragma unroll
            for (int g = 0; g < 5; ++g)
                acc[i][g] = __builtin_amdgcn_mfma_f32_16x16x32_bf16(
                    af[i], bg[g], acc[i][g], 0, 0, 0);
    }

    // Fused epilogue: lane owns j across 5 gate fragments.
    const int j = c0 + wc * 16 + fr;
    const float bfl = U_f_b[j], bfr = U_f_b[256 + j];
    const float bi = b_iou[j], bo = b_iou[256 + j], bu = b_iou[512 + j];
    #pragma unroll
    for (int i = 0; i < 4; ++i) {
        #pragma unroll
        for (int q = 0; q < 4; ++q) {
            const int p = bm0 + wr * 64 + i * 16 + l4 * 4 + q;
            if (p < M) {
                const int tl   = p >> lvl;
                const int idx  = p & ((1 << lvl) - 1);
                const int cls  = tl * (2 << lvl) + 2 * idx;
                const int node = (tree0 + tl) * NPT + (1 << lvl) - 1 + idx;
                const float flv = fsigm(acc[i][0][q] + bfl);
                const float frv = fsigm(acc[i][1][q] + bfr);
                const float iv  = fsigm(acc[i][2][q] + bi);
                const float ov  = fsigm(acc[i][3][q] + bo);
                const float uv  = ftanh(acc[i][4][q] + bu);
                const float ccl = ld_bf(c_c  + (long)cls * HS + j);
                const float ccr = ld_bf(c_c  + (long)(cls + 1) * HS + j);
                const float mhl = ld_bf(mh_c + (long)cls * HS + j);
                const float mhr = ld_bf(mh_c + (long)(cls + 1) * HS + j);
                const float cv  = iv * uv + flv * ccl + frv * ccr;
                const float hv  = ov * ftanh(cv);
                const float mhv = fmaxf(hv, fmaxf(mhl, mhr));
                const long o = (long)p * HS + j;
                h_p[o]  = __float2bfloat16(hv);
                c_p[o]  = __float2bfloat16(cv);
                mh_p[o] = __float2bfloat16(mhv);
                s_full[(long)node * HS + j] = __float2bfloat16(hv + mhv);
            }
        }
    }
}

// ---------------------------------------------------------------------------
// Final logits: out[node,0:4] = s_full[node]@lin_w + lin_b. Wave per node.
// ---------------------------------------------------------------------------
__global__ __launch_bounds__(256) void logits_k(
    const bf16* __restrict__ s_full, const float* __restrict__ lin_w,
    const float* __restrict__ lin_b, float* __restrict__ out)
{
    const int wave = threadIdx.x >> 6, lane = threadIdx.x & 63;
    const int node = blockIdx.x * 4 + wave;
    const int j0   = lane * 4;
    const us4 v = *(const us4*)(s_full + (long)node * HS + j0);
    float p0 = 0.f, p1 = 0.f, p2 = 0.f, p3 = 0.f;
    #pragma unroll
    for (int q = 0; q < 4; ++q) {
        const float s  = bits2f(v[q]);
        const float4 w = *(const float4*)(lin_w + (j0 + q) * 4);
        p0 += s * w.x; p1 += s * w.y; p2 += s * w.z; p3 += s * w.w;
    }
    #pragma unroll
    for (int m = 1; m < 64; m <<= 1) {
        p0 += __shfl_xor(p0, m); p1 += __shfl_xor(p1, m);
        p2 += __shfl_xor(p2, m); p3 += __shfl_xor(p3, m);
    }
    if (lane == 0) {
        float4 r;
        r.x = p0 + lin_b[0]; r.y = p1 + lin_b[1];
        r.z = p2 + lin_b[2]; r.w = p3 + lin_b[3];
        *(float4*)(out + (long)node * 4) = r;
    }
}

// ---------------------------------------------------------------------------
extern "C" void kernel_launch(void* const* d_in, const int* in_sizes, int n_in,
                              void* d_out, int out_size, void* d_ws, size_t ws_size,
                              hipStream_t stream) {
    const int*   wordid = (const int*)d_in[0];
    const int*   mask   = (const int*)d_in[1];
    const float* emb    = (const float*)d_in[2];
    const float* W_iou  = (const float*)d_in[3];
    const float* U_iou  = (const float*)d_in[4];
    const float* U_f_w  = (const float*)d_in[5];
    const float* U_f_b  = (const float*)d_in[6];
    const float* b_iou  = (const float*)d_in[7];
    const float* lin_w  = (const float*)d_in[8];
    const float* lin_b  = (const float*)d_in[9];
    float* out = (float*)d_out;

    const size_t wElems = (size_t)WT_ELEMS + UT_ELEMS;    // 851,968
    const size_t sElems = (size_t)NNODES * HS;            // 33,521,664
    auto need = [&](int T) -> size_t {
        return (wElems + sElems + (size_t)T * 589824) * 2;
    };
    int T = 8;
    const int cands[4] = {128, 64, 32, 16};
    for (int ci = 0; ci < 4; ++ci) {
        if (need(cands[ci]) <= ws_size) { T = cands[ci]; break; }
    }

    bf16* Wt     = (bf16*)d_ws;
    bf16* Ut     = Wt + WT_ELEMS;
    bf16* s_full = Ut + UT_ELEMS;
    const size_t aR = (size_t)T * 512 * HS;
    const size_t bR = (size_t)T * 256 * HS;
    bf16* hA  = s_full + sElems;
    bf16* cA  = hA  + aR;
    bf16* mhA = cA  + aR;
    bf16* hB  = mhA + aR;
    bf16* cB  = hB  + bR;
    bf16* mhB = cB  + bR;

    prep_w<<<(int)((wElems + 255) / 256), 256, 0, stream>>>(
        W_iou, U_f_w, U_iou, Wt, Ut);

    for (int tree0 = 0; tree0 < NTREES; tree0 += T) {
        // leaves -> A buffers
        leaf_fused<<<dim3(T * 512 / 128, 8), 256, 0, stream>>>(
            wordid, mask, emb, Wt, b_iou, hA, cA, mhA, s_full, tree0);
        // internal levels, bottom-up; ping-pong A<->B
        bool childIsA = true;
        for (int l = 8; l >= 0; --l) {
            bf16 *hc, *cc, *mc, *hp, *cp, *mp;
            if (childIsA) { hc = hA; cc = cA; mc = mhA; hp = hB; cp = cB; mp = mhB; }
            else          { hc = hB; cc = cB; mc = mhB; hp = hA; cp = cA; mp = mhA; }
            const int M = T << l;
            level_fused<<<dim3((M + 127) / 128, 8), 256, 0, stream>>>(
                hc, cc, mc, Ut, U_f_b, b_iou, hp, cp, mp, s_full, l, M, tree0);
            childIsA = !childIsA;
        }
    }
    logits_k<<<NNODES / 4, 256, 0, stream>>>(s_full, lin_w, lin_b, out);
}

// Round 7
// 419.783 us; speedup vs baseline: 4.2102x; 1.0807x over previous
//
#include <hip/hip_runtime.h>
#include <hip/hip_bf16.h>

// TreeLSTM, 128 perfect binary trees, depth 9, H=256. N=130944 nodes.
//
// R6: (1) SWAPPED-operand MFMA: mfma(bg, af) puts j in the REG dim, row in
// the LANE dim -> each lane holds 4 consecutive j of one row -> vectorized
// epilogue (us4 h/s stores, us8 packed (c,mh) store, us8 child loads).
// (2) Single-barrier 2-phase K-loop: stage(next) || compute(cur), one
// __syncthreads per K-step (implicit vmcnt/lgkm drain = pipeline wait).
//
// States: h[row][256] (GEMM input layout) + cm[row][256][2] packed (c,mh).
// ws (bf16): Wt[768*256], Ut[1280*512], s_full[N*256],
//            hA,cmA [T*512 rows], hB,cmB [T*256 rows]   (T=128: 220 MB)

#define NTREES 128
#define NPT    1023
#define HS     256
#define NNODES (NTREES * NPT)

typedef __hip_bfloat16 bf16;
typedef unsigned short us8 __attribute__((ext_vector_type(8)));
typedef unsigned short us4 __attribute__((ext_vector_type(4)));
typedef short bf16x8 __attribute__((ext_vector_type(8)));
typedef float f32x4 __attribute__((ext_vector_type(4)));

typedef __attribute__((address_space(1))) const void gvoid;
typedef __attribute__((address_space(3))) void svoid;
#define GLD16(gp, lp) \
    __builtin_amdgcn_global_load_lds((gvoid*)(gp), (svoid*)(lp), 16, 0, 0)

__device__ __forceinline__ float bits2f(unsigned short b) {
    return __uint_as_float(((unsigned)b) << 16);
}
__device__ __forceinline__ unsigned short f2bits(float x) {
    bf16 h = __float2bfloat16(x);
    return *reinterpret_cast<unsigned short*>(&h);
}
__device__ __forceinline__ float fsigm(float x) {
    return __builtin_amdgcn_rcpf(1.0f + __expf(-x));
}
__device__ __forceinline__ float ftanh(float x) {
    return 1.0f - 2.0f * __builtin_amdgcn_rcpf(1.0f + __expf(2.0f * x));
}

// ---------------------------------------------------------------------------
#define WT_ELEMS (768 * 256)
#define UT_ELEMS (1280 * 512)

__global__ __launch_bounds__(256) void prep_w(
    const float* __restrict__ W_iou, const float* __restrict__ U_f_w,
    const float* __restrict__ U_iou, bf16* __restrict__ Wt, bf16* __restrict__ Ut)
{
    const int i = blockIdx.x * 256 + threadIdx.x;
    if (i < WT_ELEMS) {
        const int n = i >> 8, k = i & 255;
        Wt[i] = __float2bfloat16(W_iou[k * 768 + n]);
    } else if (i < WT_ELEMS + UT_ELEMS) {
        const int j = i - WT_ELEMS;
        const int n = j >> 9, k = j & 511;
        const float v = (n < 512) ? U_f_w[k * 512 + n] : U_iou[k * 768 + (n - 512)];
        Ut[j] = __float2bfloat16(v);
    }
}

// ---------------------------------------------------------------------------
// Fused leaf. Tile 128 rows x (32j x 3 gates). 2-phase pipeline.
// ---------------------------------------------------------------------------
__global__ __launch_bounds__(256) void leaf_fused(
    const int* __restrict__ wordid, const int* __restrict__ mask,
    const float* __restrict__ emb, const bf16* __restrict__ Wt,
    const float* __restrict__ b_iou,
    bf16* __restrict__ h_s, bf16* __restrict__ cm_s,
    bf16* __restrict__ s_full, const int tree0)
{
    __shared__ __align__(16) short a_s[2][128 * 32];
    __shared__ __align__(16) short b_s[2][96 * 32];
    const int t    = threadIdx.x;
    const int bm0  = blockIdx.x * 128;
    const int c0   = blockIdx.y * 32;
    const int lane = t & 63, wave = t >> 6;

    // A register staging: 2 passes, row = p*64 + t/4, 8 shorts at (t%4)*8
    const int k8t = (t & 3) * 8;
    const float* aptr[2];
    int amask[2];
    #pragma unroll
    for (int p = 0; p < 2; ++p) {
        const int row  = p * 64 + (t >> 2);
        const int gr   = tree0 * 512 + bm0 + row;
        const int node = (gr >> 9) * NPT + 511 + (gr & 511);
        amask[p] = mask[node];
        aptr[p]  = emb + (long)wordid[node] * HS + k8t;
    }

    // B global_load_lds: 96 rows -> 6 instrs; waves 0..2 take 2 each.
    const int l4a = lane >> 2, k8 = (lane & 3) * 8;
    const int bCnt = (wave < 3) ? 2 : 0;
    const int bStart = wave * 2;
    const bf16* bSrc[2];
    #pragma unroll
    for (int q = 0; q < 2; ++q) {
        int rb = (bStart + q) * 16 + l4a;
        if (rb > 95) rb = 95;
        const int g = rb >> 5, jl = rb & 31;
        bSrc[q] = Wt + (long)(g * 256 + c0 + jl) * 256 + k8;
    }

    const int wr = wave >> 1, wc = wave & 1;
    const int fr = lane & 15, l4 = lane >> 4;

    f32x4 acc[4][3];
    #pragma unroll
    for (int i = 0; i < 4; ++i)
        #pragma unroll
        for (int g = 0; g < 3; ++g) acc[i][g] = (f32x4){0.f, 0.f, 0.f, 0.f};

    auto stageB = [&](int buf, int kt) {
        #pragma unroll
        for (int q = 0; q < 2; ++q)
            if (q < bCnt) GLD16(bSrc[q] + kt, &b_s[buf][(bStart + q) * 512]);
    };
    auto stageA = [&](int buf, int kt) {
        #pragma unroll
        for (int p = 0; p < 2; ++p) {
            short tmp[8];
            if (amask[p]) {
                const float4 v0 = *(const float4*)(aptr[p] + kt);
                const float4 v1 = *(const float4*)(aptr[p] + kt + 4);
                tmp[0] = (short)f2bits(v0.x); tmp[1] = (short)f2bits(v0.y);
                tmp[2] = (short)f2bits(v0.z); tmp[3] = (short)f2bits(v0.w);
                tmp[4] = (short)f2bits(v1.x); tmp[5] = (short)f2bits(v1.y);
                tmp[6] = (short)f2bits(v1.z); tmp[7] = (short)f2bits(v1.w);
            } else {
                #pragma unroll
                for (int q = 0; q < 8; ++q) tmp[q] = 0;
            }
            *(us8*)&a_s[buf][p * 2048 + t * 8] = *(us8*)&tmp[0];
        }
    };

    stageB(0, 0);
    stageA(0, 0);
    __syncthreads();
    int cur = 0;
    for (int kt = 0; kt < 256; kt += 32) {
        const int nk = kt + 32;
        if (nk < 256) { stageB(cur ^ 1, nk); stageA(cur ^ 1, nk); }
        bf16x8 af[4], bg[3];
        #pragma unroll
        for (int i = 0; i < 4; ++i)
            af[i] = *(const bf16x8*)&a_s[cur][(wr * 64 + i * 16 + fr) * 32 + l4 * 8];
        #pragma unroll
        for (int g = 0; g < 3; ++g)
            bg[g] = *(const bf16x8*)&b_s[cur][(g * 32 + wc * 16 + fr) * 32 + l4 * 8];
        #pragma unroll
        for (int i = 0; i < 4; ++i)
            #pragma unroll
            for (int g = 0; g < 3; ++g)
                acc[i][g] = __builtin_amdgcn_mfma_f32_16x16x32_bf16(
                    bg[g], af[i], acc[i][g], 0, 0, 0);   // SWAPPED: j in reg dim
        __syncthreads();
        cur ^= 1;
    }

    // Epilogue: lane owns row r (= fr within frag), 4 consecutive j (reg q).
    const int j0 = c0 + wc * 16 + l4 * 4;
    const float4 bi4 = *(const float4*)(b_iou + j0);
    const float4 bo4 = *(const float4*)(b_iou + 256 + j0);
    const float4 bu4 = *(const float4*)(b_iou + 512 + j0);
    #pragma unroll
    for (int i = 0; i < 4; ++i) {
        const int r    = bm0 + wr * 64 + i * 16 + fr;
        const int gr   = tree0 * 512 + r;
        const int node = (gr >> 9) * NPT + 511 + (gr & 511);
        us4 sh, ss; us8 scm;
        #pragma unroll
        for (int q = 0; q < 4; ++q) {
            const float iv = fsigm(acc[i][0][q] + ((const float*)&bi4)[q]);
            const float ov = fsigm(acc[i][1][q] + ((const float*)&bo4)[q]);
            const float uv = ftanh(acc[i][2][q] + ((const float*)&bu4)[q]);
            const float cv  = iv * uv;
            const float hv  = ov * ftanh(cv);
            const float mhv = fmaxf(hv, 0.0f);
            sh[q] = f2bits(hv); ss[q] = f2bits(hv + mhv);
            scm[2 * q] = f2bits(cv); scm[2 * q + 1] = f2bits(mhv);
        }
        *(us4*)(h_s + (long)r * HS + j0)        = sh;
        *(us8*)(cm_s + (long)r * 512 + j0 * 2)  = scm;
        *(us4*)(s_full + (long)node * HS + j0)  = ss;
    }
}

// ---------------------------------------------------------------------------
// Fused level. Tile 128 rows x (32j x 5 gates). 2-phase pipeline.
// ---------------------------------------------------------------------------
__global__ __launch_bounds__(256) void level_fused(
    const bf16* __restrict__ h_child, const bf16* __restrict__ cm_c,
    const bf16* __restrict__ Ut,
    const float* __restrict__ U_f_b, const float* __restrict__ b_iou,
    bf16* __restrict__ h_p, bf16* __restrict__ cm_p,
    bf16* __restrict__ s_full, const int lvl, const int M, const int tree0)
{
    __shared__ __align__(16) short a_s[2][128 * 32];
    __shared__ __align__(16) short b_s[2][160 * 32];
    const int t    = threadIdx.x;
    const int bm0  = blockIdx.x * 128;
    const int c0   = blockIdx.y * 32;
    const int lane = t & 63, wave = t >> 6;

    const int l4a = lane >> 2, k8 = (lane & 3) * 8;

    // A: 128 rows -> 8 GLD16, 2 per wave. Row -> parent p -> child-pair row.
    const bf16* aSrc[2];
    #pragma unroll
    for (int q = 0; q < 2; ++q) {
        int p = bm0 + wave * 32 + q * 16 + l4a;
        if (p >= M) p = M - 1;
        const int tl  = p >> lvl;
        const int idx = p & ((1 << lvl) - 1);
        const int cls = tl * (2 << lvl) + 2 * idx;
        aSrc[q] = h_child + (long)cls * HS + k8;  // 512 contiguous (2 children)
    }
    // B: 160 rows -> 10 GLD16; waves {3,3,2,2}.
    const int bCnt   = (wave < 2) ? 3 : 2;
    const int bStart = (wave < 2) ? wave * 3 : 6 + (wave - 2) * 2;
    const bf16* bSrc[3];
    #pragma unroll
    for (int q = 0; q < 3; ++q) {
        int rb = (bStart + q) * 16 + l4a;
        if (rb > 159) rb = 159;
        const int g = rb >> 5, jl = rb & 31;
        bSrc[q] = Ut + (long)(g * 256 + c0 + jl) * 512 + k8;
    }

    const int wr = wave >> 1, wc = wave & 1;
    const int fr = lane & 15, l4 = lane >> 4;

    f32x4 acc[4][5];
    #pragma unroll
    for (int i = 0; i < 4; ++i)
        #pragma unroll
        for (int g = 0; g < 5; ++g) acc[i][g] = (f32x4){0.f, 0.f, 0.f, 0.f};

    auto stage = [&](int buf, int kt) {
        #pragma unroll
        for (int q = 0; q < 2; ++q)
            GLD16(aSrc[q] + kt, &a_s[buf][(wave * 2 + q) * 512]);
        #pragma unroll
        for (int q = 0; q < 3; ++q)
            if (q < bCnt) GLD16(bSrc[q] + kt, &b_s[buf][(bStart + q) * 512]);
    };

    stage(0, 0);
    __syncthreads();
    int cur = 0;
    for (int kt = 0; kt < 512; kt += 32) {
        const int nk = kt + 32;
        if (nk < 512) stage(cur ^ 1, nk);
        bf16x8 af[4], bg[5];
        #pragma unroll
        for (int i = 0; i < 4; ++i)
            af[i] = *(const bf16x8*)&a_s[cur][(wr * 64 + i * 16 + fr) * 32 + l4 * 8];
        #pragma unroll
        for (int g = 0; g < 5; ++g)
            bg[g] = *(const bf16x8*)&b_s[cur][(g * 32 + wc * 16 + fr) * 32 + l4 * 8];
        #pragma unroll
        for (int i = 0; i < 4; ++i)
            #pragma unroll
            for (int g = 0; g < 5; ++g)
                acc[i][g] = __builtin_amdgcn_mfma_f32_16x16x32_bf16(
                    bg[g], af[i], acc[i][g], 0, 0, 0);   // SWAPPED: j in reg dim
        __syncthreads();
        cur ^= 1;
    }

    // Epilogue: lane owns row r, 4 consecutive j.
    const int j0 = c0 + wc * 16 + l4 * 4;
    const float4 bfl4 = *(const float4*)(U_f_b + j0);
    const float4 bfr4 = *(const float4*)(U_f_b + 256 + j0);
    const float4 bi4  = *(const float4*)(b_iou + j0);
    const float4 bo4  = *(const float4*)(b_iou + 256 + j0);
    const float4 bu4  = *(const float4*)(b_iou + 512 + j0);
    #pragma unroll
    for (int i = 0; i < 4; ++i) {
        const int r  = bm0 + wr * 64 + i * 16 + fr;
        const int rc = r < M ? r : M - 1;
        const int tl   = rc >> lvl;
        const int idx  = rc & ((1 << lvl) - 1);
        const int cls  = tl * (2 << lvl) + 2 * idx;
        const int node = (tree0 + tl) * NPT + (1 << lvl) - 1 + idx;
        const us8 cml = *(const us8*)(cm_c + (long)cls * 512 + j0 * 2);
        const us8 cmr = *(const us8*)(cm_c + (long)(cls + 1) * 512 + j0 * 2);
        us4 sh, ss; us8 scm;
        #pragma unroll
        for (int q = 0; q < 4; ++q) {
            const float flv = fsigm(acc[i][0][q] + ((const float*)&bfl4)[q]);
            const float frv = fsigm(acc[i][1][q] + ((const float*)&bfr4)[q]);
            const float iv  = fsigm(acc[i][2][q] + ((const float*)&bi4)[q]);
            const float ov  = fsigm(acc[i][3][q] + ((const float*)&bo4)[q]);
            const float uv  = ftanh(acc[i][4][q] + ((const float*)&bu4)[q]);
            const float ccl = bits2f(cml[2 * q]), mhl = bits2f(cml[2 * q + 1]);
            const float ccr = bits2f(cmr[2 * q]), mhr = bits2f(cmr[2 * q + 1]);
            const float cv  = iv * uv + flv * ccl + frv * ccr;
            const float hv  = ov * ftanh(cv);
            const float mhv = fmaxf(hv, fmaxf(mhl, mhr));
            sh[q] = f2bits(hv); ss[q] = f2bits(hv + mhv);
            scm[2 * q] = f2bits(cv); scm[2 * q + 1] = f2bits(mhv);
        }
        if (r < M) {
            *(us4*)(h_p + (long)r * HS + j0)       = sh;
            *(us8*)(cm_p + (long)r * 512 + j0 * 2) = scm;
            *(us4*)(s_full + (long)node * HS + j0) = ss;
        }
    }
}

// ---------------------------------------------------------------------------
// Final logits: out[node,0:4] = s_full[node]@lin_w + lin_b. Wave per node.
// ---------------------------------------------------------------------------
__global__ __launch_bounds__(256) void logits_k(
    const bf16* __restrict__ s_full, const float* __restrict__ lin_w,
    const float* __restrict__ lin_b, float* __restrict__ out)
{
    const int wave = threadIdx.x >> 6, lane = threadIdx.x & 63;
    const int node = blockIdx.x * 4 + wave;
    const int j0   = lane * 4;
    const us4 v = *(const us4*)(s_full + (long)node * HS + j0);
    float p0 = 0.f, p1 = 0.f, p2 = 0.f, p3 = 0.f;
    #pragma unroll
    for (int q = 0; q < 4; ++q) {
        const float s  = bits2f(v[q]);
        const float4 w = *(const float4*)(lin_w + (j0 + q) * 4);
        p0 += s * w.x; p1 += s * w.y; p2 += s * w.z; p3 += s * w.w;
    }
    #pragma unroll
    for (int m = 1; m < 64; m <<= 1) {
        p0 += __shfl_xor(p0, m); p1 += __shfl_xor(p1, m);
        p2 += __shfl_xor(p2, m); p3 += __shfl_xor(p3, m);
    }
    if (lane == 0) {
        float4 r;
        r.x = p0 + lin_b[0]; r.y = p1 + lin_b[1];
        r.z = p2 + lin_b[2]; r.w = p3 + lin_b[3];
        *(float4*)(out + (long)node * 4) = r;
    }
}

// ---------------------------------------------------------------------------
extern "C" void kernel_launch(void* const* d_in, const int* in_sizes, int n_in,
                              void* d_out, int out_size, void* d_ws, size_t ws_size,
                              hipStream_t stream) {
    const int*   wordid = (const int*)d_in[0];
    const int*   mask   = (const int*)d_in[1];
    const float* emb    = (const float*)d_in[2];
    const float* W_iou  = (const float*)d_in[3];
    const float* U_iou  = (const float*)d_in[4];
    const float* U_f_w  = (const float*)d_in[5];
    const float* U_f_b  = (const float*)d_in[6];
    const float* b_iou  = (const float*)d_in[7];
    const float* lin_w  = (const float*)d_in[8];
    const float* lin_b  = (const float*)d_in[9];
    float* out = (float*)d_out;

    const size_t wElems = (size_t)WT_ELEMS + UT_ELEMS;    // 851,968
    const size_t sElems = (size_t)NNODES * HS;            // 33,521,664
    // per-tree state elems: hA 512*256 + cmA 512*512 + hB 256*256 + cmB 256*512
    auto need = [&](int T) -> size_t {
        return (wElems + sElems + (size_t)T * 589824) * 2;
    };
    int T = 8;
    const int cands[4] = {128, 64, 32, 16};
    for (int ci = 0; ci < 4; ++ci) {
        if (need(cands[ci]) <= ws_size) { T = cands[ci]; break; }
    }

    bf16* Wt     = (bf16*)d_ws;
    bf16* Ut     = Wt + WT_ELEMS;
    bf16* s_full = Ut + UT_ELEMS;
    bf16* hA  = s_full + sElems;
    bf16* cmA = hA  + (size_t)T * 512 * HS;
    bf16* hB  = cmA + (size_t)T * 512 * HS * 2;
    bf16* cmB = hB  + (size_t)T * 256 * HS;

    prep_w<<<(int)((wElems + 255) / 256), 256, 0, stream>>>(
        W_iou, U_f_w, U_iou, Wt, Ut);

    for (int tree0 = 0; tree0 < NTREES; tree0 += T) {
        leaf_fused<<<dim3(T * 512 / 128, 8), 256, 0, stream>>>(
            wordid, mask, emb, Wt, b_iou, hA, cmA, s_full, tree0);
        bool childIsA = true;
        for (int l = 8; l >= 0; --l) {
            bf16 *hc, *cmc, *hp, *cmp;
            if (childIsA) { hc = hA; cmc = cmA; hp = hB; cmp = cmB; }
            else          { hc = hB; cmc = cmB; hp = hA; cmp = cmA; }
            const int M = T << l;
            level_fused<<<dim3((M + 127) / 128, 8), 256, 0, stream>>>(
                hc, cmc, Ut, U_f_b, b_iou, hp, cmp, s_full, l, M, tree0);
            childIsA = !childIsA;
        }
    }
    logits_k<<<NNODES / 4, 256, 0, stream>>>(s_full, lin_w, lin_b, out);
}